// Round 19
// baseline (220.117 us; speedup 1.0000x reference)
//
#include <hip/hip_runtime.h>
#include <hip/hip_bf16.h>

typedef __attribute__((ext_vector_type(8))) short s16x8;
typedef __attribute__((ext_vector_type(4))) float f32x4;

__device__ __forceinline__ float bf_lo(unsigned u){ return __uint_as_float(u << 16); }
__device__ __forceinline__ float bf_hi(unsigned u){ return __uint_as_float(u & 0xFFFF0000u); }
__device__ __forceinline__ unsigned short f2bf(float f){
  unsigned u = __float_as_uint(f);
  u += 0x7FFFu + ((u >> 16) & 1u);
  return (unsigned short)(u >> 16);
}
__device__ __forceinline__ unsigned pk2(float lo, float hi){
  return (unsigned)f2bf(lo) | ((unsigned)f2bf(hi) << 16);
}
__device__ __forceinline__ float bf2f(unsigned short s){ return __uint_as_float(((unsigned)s) << 16); }
__device__ __forceinline__ s16x8 frg(uint4 u){ union { uint4 a; s16x8 b; } x; x.a = u; return x.b; }

#define VX(row) ((((row) & 3) << 4))

__device__ __forceinline__ float wredsum(float v){
  #pragma unroll
  for (int m = 32; m > 0; m >>= 1) v += __shfl_xor(v, m, 64);
  return v;
}
__device__ __forceinline__ float wredmax(float v){
  #pragma unroll
  for (int m = 32; m > 0; m >>= 1) v = fmaxf(v, __shfl_xor(v, m, 64));
  return v;
}

// ---------------- fused prep: starts + all weight transposes ----------------
__global__ void k_prep_all(const float* __restrict__ wq, const float* __restrict__ wk,
                           const float* __restrict__ wv, const float* __restrict__ wo,
                           const float* __restrict__ w1, const float* __restrict__ w2,
                           const int* __restrict__ mol, int N,
                           unsigned short* __restrict__ wt,
                           unsigned short* __restrict__ w1t,
                           unsigned short* __restrict__ w2t,
                           int* __restrict__ starts){
  __shared__ float T[32][33];
  const int bid = blockIdx.x;
  const int t = threadIdx.x;
  if (bid < 512){
    const int mat = bid >> 7, h = (bid >> 4) & 7, tile = bid & 15;
    const int ti = tile >> 2, tj = tile & 3;
    const float* src; int rs;
    if (mat == 0){ src = wq + h * 128; rs = 1024; }
    else if (mat == 1){ src = wk + h * 128; rs = 1024; }
    else if (mat == 2){ src = wv + h * 128; rs = 1024; }
    else { src = wo + h * 16384; rs = 128; }
    for (int i = t; i < 1024; i += 256){
      const int r = i >> 5, cc = i & 31;
      T[r][cc] = src[(size_t)(tj * 32 + r) * rs + ti * 32 + cc];
    }
    __syncthreads();
    unsigned short* dst = wt + ((mat * 8 + h) << 14);
    for (int i = t; i < 1024; i += 256){
      const int orr = i >> 5, occ = i & 31;
      dst[(ti * 32 + orr) * 128 + tj * 32 + occ] = f2bf(T[occ][orr]);
    }
  } else if (bid < 544){
    const int bb = bid - 512;
    const int ti = bb >> 2, tj = bb & 3;
    for (int i = t; i < 1024; i += 256){
      const int r = i >> 5, cc = i & 31;
      T[r][cc] = w1[(size_t)(tj * 32 + r) * 256 + ti * 32 + cc];
    }
    __syncthreads();
    for (int i = t; i < 1024; i += 256){
      const int orr = i >> 5, occ = i & 31;
      w1t[(ti * 32 + orr) * 128 + tj * 32 + occ] = f2bf(T[occ][orr]);
    }
  } else if (bid < 576){
    const int bb = bid - 544;
    const int ti = bb >> 3, tj = bb & 7;
    for (int i = t; i < 1024; i += 256){
      const int r = i >> 5, cc = i & 31;
      T[r][cc] = w2[(size_t)(tj * 32 + r) * 128 + ti * 32 + cc];
    }
    __syncthreads();
    for (int i = t; i < 1024; i += 256){
      const int orr = i >> 5, occ = i & 31;
      w2t[(ti * 32 + orr) * 256 + tj * 32 + occ] = f2bf(T[occ][orr]);
    }
  } else {
    for (int i = t; i <= 256; i += 256){
      int lo = 0, hi = N;
      while (lo < hi){ const int m = (lo + hi) >> 1; if (mol[m] < i) lo = m + 1; else hi = m; }
      starts[i] = lo;
    }
  }
}

// legacy standalone starts (mode 0)
__global__ void k_starts(const int* __restrict__ mol, int N, int* __restrict__ starts){
  const int t = blockIdx.x * blockDim.x + threadIdx.x;
  if (t <= 256){
    int lo = 0, hi = N;
    while (lo < hi){ const int m = (lo + hi) >> 1; if (mol[m] < t) lo = m + 1; else hi = m; }
    starts[t] = lo;
  }
}

// softmax over S[10] -> normalized bf16 P[10] (pairs packed in uint2)
#define SM2P(Sx, Pd) do { \
    float mx = -3.0e38f; \
    _Pragma("unroll") \
    for (int kt = 0; kt < 10; ++kt) if (kt < KTn){ \
      _Pragma("unroll") \
      for (int r = 0; r < 4; ++r){ \
        const int key = 16 * kt + 4 * a + r; \
        const float sv = (key < n) ? Sx[kt][r] * SCALE : -1.0e30f; \
        Sx[kt][r] = sv; mx = fmaxf(mx, sv); \
      } \
    } \
    mx = fmaxf(mx, __shfl_xor(mx, 16, 64)); \
    mx = fmaxf(mx, __shfl_xor(mx, 32, 64)); \
    float sum = 0.f; \
    _Pragma("unroll") \
    for (int kt = 0; kt < 10; ++kt) if (kt < KTn){ \
      _Pragma("unroll") \
      for (int r = 0; r < 4; ++r){ \
        const float e = __expf(Sx[kt][r] - mx); \
        Sx[kt][r] = e; sum += e; \
      } \
    } \
    sum += __shfl_xor(sum, 16, 64); \
    sum += __shfl_xor(sum, 32, 64); \
    const float inv = 1.f / sum; \
    _Pragma("unroll") \
    for (int kt = 0; kt < 10; ++kt) if (kt < KTn){ \
      uint2 u; \
      u.x = pk2(Sx[kt][0] * inv, Sx[kt][1] * inv); \
      u.y = pk2(Sx[kt][2] * inv, Sx[kt][3] * inv); \
      Pd[kt] = u; \
    } \
  } while(0)

// store P[10] (uint2 pairs) into this wave's slab + pad-zero tail tile
#define PSTORE(Pd) do { \
    _Pragma("unroll") \
    for (int kt = 0; kt < 10; ++kt) if (kt < KTn) \
      *(uint2*)(&SH[pb + c * 320 + ((((16 * kt + 4 * a) << 1)) ^ VX(c))]) = Pd[kt]; \
    if (KTn & 1){ \
      uint2 z; z.x = 0u; z.y = 0u; \
      *(uint2*)(&SH[pb + c * 320 + ((((16 * KTn + 4 * a) << 1)) ^ VX(c))]) = z; \
    } \
  } while(0)

// ---------------- kernel B3: 80KB-LDS attention, 2 blocks/CU ----------------
// r19: r18 (assoc fusion + dual-q S-fusion) + dual-pass AO fusion: for dual
// waves, VW^T fragments are read ONCE and feed AO0/AO1 MFMA pairs (saves 40
// uint4 LDS reads/dual-wave; P0 fragments prefetched statically-indexed to
// avoid rule-#20 scratch). Spill canary: FETCH > 150MB => revert.
// LDS [0,40960): X rows -> K rows (bar2) -> 8 P slabs (bar5)
//     [40960,81920): V rows [key][dv] (256B, K-swz) -> VW^T [d][k] (320B, VX)
// Q round-trips global in blocked B-frag layout (45056 B/block).
// NOTE negatives: cvt_pk asm(r6), setprio(r6), 1024thr(r8 spill), XCD remap(r14).
__global__ __launch_bounds__(512, 4) void k_attn3(
    const float* __restrict__ x, const unsigned short* __restrict__ wt,
    const float* __restrict__ bqg, const float* __restrict__ bkg, const float* __restrict__ bvg,
    const int* __restrict__ starts,
    unsigned short* __restrict__ aoh, unsigned short* __restrict__ qg, int N, int NR)
{
  __shared__ unsigned char SH[81920];
  const int bid = blockIdx.x;
  const int b = bid >> 3, h = bid & 7;
  const int st = starts[b];
  const int n  = starts[b + 1] - st;        // 96..160
  const int KTn = (n + 15) >> 4;
  const int QTn = (n + 16) >> 4;
  const int t = threadIdx.x, w = t >> 6, l = t & 63;
  const int c = l & 15, a = l >> 4;
  const f32x4 Z4 = {0.f, 0.f, 0.f, 0.f};
  unsigned char* Qg = (unsigned char*)qg + (size_t)bid * 45056;

  // ---- stage X (region A) ----
  for (int i = t; i < 5120; i += 512){
    const int r = i >> 5, c4 = i & 31;
    uint2 v; v.x = 0u; v.y = 0u;
    if (r < n){
      const float4 xv = *(const float4*)(x + ((size_t)(st + r) << 7) + (c4 << 2));
      v.x = pk2(xv.x, xv.y); v.y = pk2(xv.z, xv.w);
    }
    *(uint2*)(&SH[r * 256 + ((c4 * 8) ^ ((r & 7) << 4))]) = v;
  }
  __syncthreads();                                    // bar1

  const unsigned short* wqt = wt + ((0 * 8 + h) << 14);
  const unsigned short* wkt = wt + ((1 * 8 + h) << 14);
  const unsigned short* wvt = wt + ((2 * 8 + h) << 14);
  const unsigned short* wot = wt + ((3 * 8 + h) << 14);

  // ---- Q proj -> global blocked layout ----
  {
    f32x4 CQ[11];
    #pragma unroll
    for (int qt = 0; qt < 11; ++qt) CQ[qt] = Z4;
    #pragma unroll
    for (int kw = 0; kw < 4; ++kw){
      const s16x8 aq = frg(*(const uint4*)(wqt + (16 * w + c) * 128 + kw * 32 + a * 8));
      #pragma unroll
      for (int qt = 0; qt < 11; ++qt) if (qt < QTn){
        const int r0 = 16 * qt + c;
        const int row = r0 < 160 ? r0 : 159;
        const s16x8 xf = frg(*(const uint4*)(&SH[row * 256 + ((kw * 64 + a * 16) ^ ((row & 7) << 4))]));
        CQ[qt] = __builtin_amdgcn_mfma_f32_16x16x32_bf16(aq, xf, CQ[qt], 0, 0, 0);
      }
    }
    const float4 bq4 = *(const float4*)(bqg + h * 128 + 16 * w + 4 * a);
    const int kwq = w >> 1, ksq = 2 * (w & 1) + (a >> 1), half = a & 1;
    #pragma unroll
    for (int qt = 0; qt < 11; ++qt) if (qt < QTn){
      uint2 u;
      u.x = pk2(CQ[qt][0] + bq4.x, CQ[qt][1] + bq4.y);
      u.y = pk2(CQ[qt][2] + bq4.z, CQ[qt][3] + bq4.w);
      *(uint2*)(Qg + ((((qt * 4 + kwq) * 4 + ksq) * 16 + c) << 4) + 8 * half) = u;
    }
  }
  // ---- fused K+V projection: ONE X-read feeds both MFMAs ----
  {
    f32x4 CK[10], CV[10];
    #pragma unroll
    for (int kt = 0; kt < 10; ++kt){ CK[kt] = Z4; CV[kt] = Z4; }
    #pragma unroll
    for (int kw = 0; kw < 4; ++kw){
      const int wofs = (16 * w + c) * 128 + kw * 32 + a * 8;
      const s16x8 ak  = frg(*(const uint4*)(wkt + wofs));
      const s16x8 bv8 = frg(*(const uint4*)(wvt + wofs));
      #pragma unroll
      for (int kt = 0; kt < 10; ++kt) if (kt < KTn){
        const int row = 16 * kt + c;
        const s16x8 xf = frg(*(const uint4*)(&SH[row * 256 + ((kw * 64 + a * 16) ^ ((row & 7) << 4))]));
        CK[kt] = __builtin_amdgcn_mfma_f32_16x16x32_bf16(ak, xf, CK[kt], 0, 0, 0);
        CV[kt] = __builtin_amdgcn_mfma_f32_16x16x32_bf16(xf, bv8, CV[kt], 0, 0, 0);
      }
    }
    // V -> region B ROW-MAJOR [key][dv], stride 256, K-style swizzle.
    const float bvv = bvg[h * 128 + 16 * w + c];
    #pragma unroll
    for (int kt = 0; kt < 10; ++kt) if (kt < KTn){
      #pragma unroll
      for (int r = 0; r < 4; ++r){
        const int key = 16 * kt + 4 * a + r;
        *(unsigned short*)(&SH[40960 + key * 256 +
            ((((16 * w + c) << 1)) ^ ((key & 7) << 4))]) = f2bf(CV[kt][r] + bvv);
      }
    }
    __syncthreads();                                  // bar2: all X reads done
    const float4 bk4 = *(const float4*)(bkg + h * 128 + 16 * w + 4 * a);
    #pragma unroll
    for (int kt = 0; kt < 10; ++kt) if (kt < KTn){
      const int key = 16 * kt + c;
      uint2 u;
      u.x = pk2(CK[kt][0] + bk4.x, CK[kt][1] + bk4.y);
      u.y = pk2(CK[kt][2] + bk4.z, CK[kt][3] + bk4.w);
      *(uint2*)(&SH[key * 256 + ((32 * w + 8 * a) ^ ((key & 7) << 4))]) = u;
    }
  }
  __syncthreads();                                    // bar3: K + V ready

  // ---- S + softmax; dual-q fused when both tiles exist ----
  const float SCALE = 0.08838834764831845f;
  uint2 P[2][10];
  const int qt0 = w, qt1 = w + 8;
  const bool dual = (qt1 < QTn);
  if (qt0 < QTn){
    if (dual){
      // dual: q0 = 16*qt0+c <= 127 (w<=2 here) -> no phantom patch on bu0
      const int q1 = 16 * qt1 + c;
      f32x4 Sa[10], Sb[10];
      #pragma unroll
      for (int kt = 0; kt < 10; ++kt){ Sa[kt] = Z4; Sb[kt] = Z4; }
      #pragma unroll
      for (int kw = 0; kw < 4; ++kw){
        const uint4 bu0 = *(const uint4*)(Qg + ((((qt0 * 4 + kw) * 4 + a) * 16 + c) << 4));
        uint4 bu1 = *(const uint4*)(Qg + ((((qt1 * 4 + kw) * 4 + a) * 16 + c) << 4));
        if (q1 == 160){
          const float4 p0 = *(const float4*)(bqg + h * 128 + kw * 32 + 8 * a);
          const float4 p1 = *(const float4*)(bqg + h * 128 + kw * 32 + 8 * a + 4);
          bu1.x = pk2(p0.x, p0.y); bu1.y = pk2(p0.z, p0.w);
          bu1.z = pk2(p1.x, p1.y); bu1.w = pk2(p1.z, p1.w);
        }
        const s16x8 qa = frg(bu0);
        const s16x8 qb = frg(bu1);
        #pragma unroll
        for (int kt = 0; kt < 10; ++kt) if (kt < KTn){
          const int krow = 16 * kt + c;
          const s16x8 kf = frg(*(const uint4*)(&SH[krow * 256 + ((kw * 64 + a * 16) ^ ((krow & 7) << 4))]));
          Sa[kt] = __builtin_amdgcn_mfma_f32_16x16x32_bf16(kf, qa, Sa[kt], 0, 0, 0);
          Sb[kt] = __builtin_amdgcn_mfma_f32_16x16x32_bf16(kf, qb, Sb[kt], 0, 0, 0);
        }
      }
      SM2P(Sa, P[0]);
      SM2P(Sb, P[1]);
    } else {
      // single: q0 <= 127 -> no phantom patch needed
      f32x4 Sa[10];
      #pragma unroll
      for (int kt = 0; kt < 10; ++kt) Sa[kt] = Z4;
      #pragma unroll
      for (int kw = 0; kw < 4; ++kw){
        const uint4 bu0 = *(const uint4*)(Qg + ((((qt0 * 4 + kw) * 4 + a) * 16 + c) << 4));
        const s16x8 qa = frg(bu0);
        #pragma unroll
        for (int kt = 0; kt < 10; ++kt) if (kt < KTn){
          const int krow = 16 * kt + c;
          const s16x8 kf = frg(*(const uint4*)(&SH[krow * 256 + ((kw * 64 + a * 16) ^ ((krow & 7) << 4))]));
          Sa[kt] = __builtin_amdgcn_mfma_f32_16x16x32_bf16(kf, qa, Sa[kt], 0, 0, 0);
        }
      }
      SM2P(Sa, P[0]);
    }
  }

  // ---- VW = V · Wo_h : wave w owns d-tile w (C[key][d], 40 MFMAs) ----
  f32x4 CW[10];
  #pragma unroll
  for (int kt = 0; kt < 10; ++kt) CW[kt] = Z4;
  #pragma unroll
  for (int kw = 0; kw < 4; ++kw){
    const s16x8 wf = frg(*(const uint4*)(wot + (16 * w + c) * 128 + kw * 32 + a * 8));
    #pragma unroll
    for (int kt = 0; kt < 10; ++kt) if (kt < KTn){
      const int row = 16 * kt + c;
      const s16x8 vf = frg(*(const uint4*)(&SH[40960 + row * 256 + ((kw * 64 + a * 16) ^ ((row & 7) << 4))]));
      CW[kt] = __builtin_amdgcn_mfma_f32_16x16x32_bf16(vf, wf, CW[kt], 0, 0, 0);
    }
  }
  __syncthreads();                                    // bar4: V reads done, K dead

  // store VW^T [d][k] stride 320, VX swizzle over region B
  #pragma unroll
  for (int kt = 0; kt < 10; ++kt) if (kt < KTn){
    uint2 u;
    u.x = pk2(CW[kt][0], CW[kt][1]);
    u.y = pk2(CW[kt][2], CW[kt][3]);
    *(uint2*)(&SH[40960 + (16 * w + c) * 320 + ((((16 * kt + 4 * a) << 1)) ^ VX(c))]) = u;
  }
  // pad-zero the VW^T tail key-tile when KTn odd (r17 NaN fix)
  if (KTn & 1){
    uint2 z; z.x = 0u; z.y = 0u;
    *(uint2*)(&SH[40960 + (16 * w + c) * 320 + ((((16 * KTn + 4 * a) << 1)) ^ VX(c))]) = z;
  }
  __syncthreads();                                    // bar5: VW^T ready, slabs free

  // ---- AO = P·VW ; dual-pass fused VW^T reads when both tiles exist ----
  const int pb = w * 5120;
  const int kwn = (KTn + 1) >> 1;
  if (qt0 < QTn){
    if (dual){
      const int q1 = 16 * qt1 + c;
      // store P0 slab, prefetch its A-fragments (statically indexed)
      PSTORE(P[0]);
      uint4 pf0[5];
      #pragma unroll
      for (int k2 = 0; k2 < 5; ++k2) if (k2 < kwn)
        pf0[k2] = *(const uint4*)(&SH[pb + c * 320 + ((k2 * 64 + a * 16) ^ VX(c))]);
      // overwrite slab with P1
      PSTORE(P[1]);
      f32x4 AO0[8], AO1[8];
      #pragma unroll
      for (int dt = 0; dt < 8; ++dt){ AO0[dt] = Z4; AO1[dt] = Z4; }
      #pragma unroll
      for (int k2 = 0; k2 < 5; ++k2) if (k2 < kwn){
        const s16x8 pf1 = frg(*(const uint4*)(&SH[pb + c * 320 + ((k2 * 64 + a * 16) ^ VX(c))]));
        const s16x8 pf0f = frg(pf0[k2]);
        #pragma unroll
        for (int dt = 0; dt < 8; ++dt){
          const s16x8 vwf = frg(*(const uint4*)(&SH[40960 + (16 * dt + c) * 320 + ((k2 * 64 + a * 16) ^ VX(c))]));
          AO0[dt] = __builtin_amdgcn_mfma_f32_16x16x32_bf16(vwf, pf0f, AO0[dt], 0, 0, 0);
          AO1[dt] = __builtin_amdgcn_mfma_f32_16x16x32_bf16(vwf, pf1, AO1[dt], 0, 0, 0);
        }
      }
      // pass0 store: q0 = 16*qt0+c <= 47 < 96 <= n always
      {
        const int grow = st + 16 * qt0 + c;
        unsigned short* dst = aoh + (((size_t)h * NR + grow) << 7);
        #pragma unroll
        for (int dt = 0; dt < 8; ++dt){
          uint2 u; u.x = pk2(AO0[dt][0], AO0[dt][1]); u.y = pk2(AO0[dt][2], AO0[dt][3]);
          *(uint2*)(dst + 16 * dt + 4 * a) = u;
        }
      }
      if (q1 <= n){
        const int grow = (q1 < n) ? (st + q1) : (N + b);
        unsigned short* dst = aoh + (((size_t)h * NR + grow) << 7);
        #pragma unroll
        for (int dt = 0; dt < 8; ++dt){
          uint2 u; u.x = pk2(AO1[dt][0], AO1[dt][1]); u.y = pk2(AO1[dt][2], AO1[dt][3]);
          *(uint2*)(dst + 16 * dt + 4 * a) = u;
        }
      }
    } else {
      const int q = 16 * qt0 + c;
      PSTORE(P[0]);
      f32x4 AO[8];
      #pragma unroll
      for (int dt = 0; dt < 8; ++dt) AO[dt] = Z4;
      #pragma unroll
      for (int k2 = 0; k2 < 5; ++k2) if (k2 < kwn){
        const s16x8 pf = frg(*(const uint4*)(&SH[pb + c * 320 + ((k2 * 64 + a * 16) ^ VX(c))]));
        #pragma unroll
        for (int dt = 0; dt < 8; ++dt){
          const s16x8 vwf = frg(*(const uint4*)(&SH[40960 + (16 * dt + c) * 320 + ((k2 * 64 + a * 16) ^ VX(c))]));
          AO[dt] = __builtin_amdgcn_mfma_f32_16x16x32_bf16(vwf, pf, AO[dt], 0, 0, 0);
        }
      }
      if (q <= n){
        const int grow = (q < n) ? (st + q) : (N + b);
        unsigned short* dst = aoh + (((size_t)h * NR + grow) << 7);
        #pragma unroll
        for (int dt = 0; dt < 8; ++dt){
          uint2 u; u.x = pk2(AO[dt][0], AO[dt][1]); u.y = pk2(AO[dt][2], AO[dt][3]);
          *(uint2*)(dst + 16 * dt + 4 * a) = u;
        }
      }
    }
  }
}

// ---------------- kernel B: round-9 proven attention (mode 1/2 fallback) ----
__global__ __launch_bounds__(512, 2) void k_attn(
    const float* __restrict__ x, const unsigned short* __restrict__ wt,
    const float* __restrict__ bqg, const float* __restrict__ bkg, const float* __restrict__ bvg,
    const int* __restrict__ starts,
    unsigned short* aoh, float* aof, int useslab, int N, int NR)
{
  __shared__ unsigned char SH[163840];
  const int b = blockIdx.x >> 3, h = blockIdx.x & 7;
  const int st = starts[b];
  const int n  = starts[b + 1] - st;
  const int KTn = (n + 15) >> 4;
  const int QTn = (n + 16) >> 4;
  const int t = threadIdx.x, w = t >> 6, l = t & 63;
  const int c = l & 15, a = l >> 4;
  const f32x4 Z4 = {0.f, 0.f, 0.f, 0.f};

  for (int i = t; i < 5120; i += 512){
    const int r = i >> 5, c4 = i & 31;
    uint2 v; v.x = 0u; v.y = 0u;
    if (r < n){
      const float4 xv = *(const float4*)(x + ((size_t)(st + r) << 7) + (c4 << 2));
      v.x = pk2(xv.x, xv.y); v.y = pk2(xv.z, xv.w);
    }
    *(uint2*)(&SH[r * 256 + ((c4 * 8) ^ ((r & 7) << 4))]) = v;
  }
  if (KTn & 1){
    const int dv = t >> 2, kq = t & 3;
    uint2 z; z.x = 0u; z.y = 0u;
    if (dv < 128) *(uint2*)(&SH[81920 + dv * 320 + ((KTn * 32 + kq * 8) ^ VX(dv))]) = z;
  }
  __syncthreads();

  const unsigned short* wqt = wt + ((0 * 8 + h) << 14);
  const unsigned short* wkt = wt + ((1 * 8 + h) << 14);
  const unsigned short* wvt = wt + ((2 * 8 + h) << 14);
  const unsigned short* wot = wt + ((3 * 8 + h) << 14);

  {
    f32x4 CK[10], CV[10];
    #pragma unroll
    for (int kt = 0; kt < 10; ++kt){ CK[kt] = Z4; CV[kt] = Z4; }
    #pragma unroll
    for (int kw = 0; kw < 4; ++kw){
      const int wofs = (16 * w + c) * 128 + kw * 32 + a * 8;
      const s16x8 ak  = frg(*(const uint4*)(wkt + wofs));
      const s16x8 bv8 = frg(*(const uint4*)(wvt + wofs));
      #pragma unroll
      for (int kt = 0; kt < 10; ++kt) if (kt < KTn){
        const int row = 16 * kt + c;
        const s16x8 xf = frg(*(const uint4*)(&SH[row * 256 + ((kw * 64 + a * 16) ^ ((row & 7) << 4))]));
        CK[kt] = __builtin_amdgcn_mfma_f32_16x16x32_bf16(ak, xf, CK[kt], 0, 0, 0);
        CV[kt] = __builtin_amdgcn_mfma_f32_16x16x32_bf16(xf, bv8, CV[kt], 0, 0, 0);
      }
    }
    const float4 bk4 = *(const float4*)(bkg + h * 128 + 16 * w + 4 * a);
    const float  bvv = bvg[h * 128 + 16 * w + c];
    #pragma unroll
    for (int kt = 0; kt < 10; ++kt) if (kt < KTn){
      const int key = 16 * kt + c;
      uint2 u;
      u.x = pk2(CK[kt][0] + bk4.x, CK[kt][1] + bk4.y);
      u.y = pk2(CK[kt][2] + bk4.z, CK[kt][3] + bk4.w);
      *(uint2*)(&SH[40960 + key * 256 + ((32 * w + 8 * a) ^ ((key & 7) << 4))]) = u;
      uint2 v;
      v.x = pk2(CV[kt][0] + bvv, CV[kt][1] + bvv);
      v.y = pk2(CV[kt][2] + bvv, CV[kt][3] + bvv);
      *(uint2*)(&SH[81920 + (16 * w + c) * 320 + ((((16 * kt + 4 * a) << 1)) ^ VX(c))]) = v;
    }
  }
  {
    f32x4 CQ[11];
    #pragma unroll
    for (int qt = 0; qt < 11; ++qt) CQ[qt] = Z4;
    #pragma unroll
    for (int kw = 0; kw < 4; ++kw){
      const s16x8 aq = frg(*(const uint4*)(wqt + (16 * w + c) * 128 + kw * 32 + a * 8));
      #pragma unroll
      for (int qt = 0; qt < 11; ++qt) if (qt < QTn){
        const int r0 = 16 * qt + c;
        const int row = r0 < 160 ? r0 : 159;
        const s16x8 xf = frg(*(const uint4*)(&SH[row * 256 + ((kw * 64 + a * 16) ^ ((row & 7) << 4))]));
        CQ[qt] = __builtin_amdgcn_mfma_f32_16x16x32_bf16(aq, xf, CQ[qt], 0, 0, 0);
      }
    }
    __syncthreads();
    const float4 bq4 = *(const float4*)(bqg + h * 128 + 16 * w + 4 * a);
    #pragma unroll
    for (int qt = 0; qt < 11; ++qt) if (qt < QTn){
      const int q = 16 * qt + c;
      if (q < 160){
        uint2 u;
        u.x = pk2(CQ[qt][0] + bq4.x, CQ[qt][1] + bq4.y);
        u.y = pk2(CQ[qt][2] + bq4.z, CQ[qt][3] + bq4.w);
        *(uint2*)(&SH[q * 256 + ((32 * w + 8 * a) ^ ((q & 7) << 4))]) = u;
      }
    }
  }
  __syncthreads();

  const float SCALE = 0.08838834764831845f;
  const int pb = 122880 + w * 5120;
  for (int qt = w; qt < QTn; qt += 8){
    const int q = 16 * qt + c;
    f32x4 S[10];
    #pragma unroll
    for (int kt = 0; kt < 10; ++kt) S[kt] = Z4;
    #pragma unroll
    for (int kw = 0; kw < 4; ++kw){
      const int qrow = q < 160 ? q : 159;
      uint4 bu = *(const uint4*)(&SH[qrow * 256 + ((kw * 64 + a * 16) ^ ((qrow & 7) << 4))]);
      if (q == 160){
        const float4 p0 = *(const float4*)(bqg + h * 128 + kw * 32 + a * 8);
        const float4 p1 = *(const float4*)(bqg + h * 128 + kw * 32 + a * 8 + 4);
        bu.x = pk2(p0.x, p0.y); bu.y = pk2(p0.z, p0.w);
        bu.z = pk2(p1.x, p1.y); bu.w = pk2(p1.z, p1.w);
      }
      const s16x8 qb = frg(bu);
      #pragma unroll
      for (int kt = 0; kt < 10; ++kt) if (kt < KTn){
        const int krow = 16 * kt + c;
        const s16x8 kf = frg(*(const uint4*)(&SH[40960 + krow * 256 + ((kw * 64 + a * 16) ^ ((krow & 7) << 4))]));
        S[kt] = __builtin_amdgcn_mfma_f32_16x16x32_bf16(kf, qb, S[kt], 0, 0, 0);
      }
    }
    float mx = -3.0e38f;
    #pragma unroll
    for (int kt = 0; kt < 10; ++kt) if (kt < KTn){
      #pragma unroll
      for (int r = 0; r < 4; ++r){
        const int key = 16 * kt + 4 * a + r;
        const float sv = (key < n) ? S[kt][r] * SCALE : -1.0e30f;
        S[kt][r] = sv; mx = fmaxf(mx, sv);
      }
    }
    mx = fmaxf(mx, __shfl_xor(mx, 16, 64));
    mx = fmaxf(mx, __shfl_xor(mx, 32, 64));
    float sum = 0.f;
    #pragma unroll
    for (int kt = 0; kt < 10; ++kt) if (kt < KTn){
      #pragma unroll
      for (int r = 0; r < 4; ++r){
        const float e = __expf(S[kt][r] - mx);
        S[kt][r] = e; sum += e;
      }
    }
    sum += __shfl_xor(sum, 16, 64);
    sum += __shfl_xor(sum, 32, 64);
    const float inv = 1.f / sum;
    #pragma unroll
    for (int kt = 0; kt < 10; ++kt) if (kt < KTn){
      uint2 u;
      u.x = pk2(S[kt][0] * inv, S[kt][1] * inv);
      u.y = pk2(S[kt][2] * inv, S[kt][3] * inv);
      *(uint2*)(&SH[pb + c * 320 + ((((16 * kt + 4 * a) << 1)) ^ VX(c))]) = u;
    }
    if (KTn & 1){
      uint2 z; z.x = 0u; z.y = 0u;
      *(uint2*)(&SH[pb + c * 320 + ((((16 * KTn + 4 * a) << 1)) ^ VX(c))]) = z;
    }
    f32x4 O[8];
    #pragma unroll
    for (int dt = 0; dt < 8; ++dt) O[dt] = Z4;
    const int kwn = (KTn + 1) >> 1;
    for (int k2 = 0; k2 < kwn; ++k2){
      const s16x8 pf = frg(*(const uint4*)(&SH[pb + c * 320 + ((k2 * 64 + a * 16) ^ VX(c))]));
      #pragma unroll
      for (int dt = 0; dt < 8; ++dt){
        const s16x8 vf = frg(*(const uint4*)(&SH[81920 + (16 * dt + c) * 320 + ((k2 * 64 + a * 16) ^ VX(c))]));
        O[dt] = __builtin_amdgcn_mfma_f32_16x16x32_bf16(vf, pf, O[dt], 0, 0, 0);
      }
    }
    #pragma unroll
    for (int dt = 0; dt < 8; ++dt){
      uint2 u; u.x = pk2(O[dt][0], O[dt][1]); u.y = pk2(O[dt][2], O[dt][3]);
      *(uint2*)(&SH[pb + c * 320 + ((((16 * dt + 4 * a) << 1)) ^ VX(c))]) = u;
    }
    f32x4 AO[8];
    #pragma unroll
    for (int dt = 0; dt < 8; ++dt) AO[dt] = Z4;
    #pragma unroll
    for (int kw = 0; kw < 4; ++kw){
      const s16x8 ob = frg(*(const uint4*)(&SH[pb + c * 320 + ((kw * 64 + a * 16) ^ VX(c))]));
      #pragma unroll
      for (int dt = 0; dt < 8; ++dt){
        const s16x8 wf = frg(*(const uint4*)(wot + (16 * dt + c) * 128 + kw * 32 + a * 8));
        AO[dt] = __builtin_amdgcn_mfma_f32_16x16x32_bf16(wf, ob, AO[dt], 0, 0, 0);
      }
    }
    if (q <= n){
      const int grow = (q < n) ? (st + q) : (N + b);
      if (useslab){
        unsigned short* dst = aoh + (((size_t)h * NR + grow) << 7);
        #pragma unroll
        for (int dt = 0; dt < 8; ++dt){
          uint2 u; u.x = pk2(AO[dt][0], AO[dt][1]); u.y = pk2(AO[dt][2], AO[dt][3]);
          *(uint2*)(dst + 16 * dt + 4 * a) = u;
        }
      } else {
        float* dstf = aof + ((size_t)grow << 7);
        #pragma unroll
        for (int dt = 0; dt < 8; ++dt){
          #pragma unroll
          for (int r = 0; r < 4; ++r)
            atomicAdd(dstf + 16 * dt + 4 * a + r, AO[dt][r]);
        }
      }
    }
  }
}

// ---------------- kernel C: MFMA residual+LN1+FFN+LN2+readout ----------------
__global__ __launch_bounds__(512, 4) void k_ffn(
    const float* __restrict__ x, const int* __restrict__ mol,
    const unsigned short* aoh, const float* aof, int useslab,
    const float* __restrict__ bo,
    const unsigned short* __restrict__ w1t, const unsigned short* __restrict__ w2t,
    const float* __restrict__ b1, const float* __restrict__ b2,
    const float* __restrict__ g1, const float* __restrict__ be1,
    const float* __restrict__ g2, const float* __restrict__ be2,
    const int* __restrict__ starts, float* __restrict__ acc,
    int N, int NR)
{
  __shared__ unsigned char FS[49152];
  const int t = threadIdx.x, w = t >> 6, l = t & 63;
  const int c = l & 15, a = l >> 4;
  const int rbase = blockIdx.x * 64;
  const f32x4 Z4 = {0.f, 0.f, 0.f, 0.f};

  const float2 bo2  = *(const float2*)(bo  + 2 * l);
  const float2 g12  = *(const float2*)(g1  + 2 * l);
  const float2 be12 = *(const float2*)(be1 + 2 * l);

  float hreg[8][2];

  #pragma unroll 1
  for (int i = 0; i < 8; ++i){
    const int lr = w * 8 + i;
    const int row = rbase + lr;
    float v0 = 0.f, v1 = 0.f;
    if (row < NR){
      if (row < N){
        const float2 xv = *(const float2*)(x + ((size_t)row << 7) + 2 * l);
        v0 = xv.x; v1 = xv.y;
      }
      if (useslab){
        #pragma unroll
        for (int hh = 0; hh < 8; ++hh){
          const unsigned u = *(const unsigned*)(aoh + (((size_t)hh * NR + row) << 7) + 2 * l);
          v0 += bf_lo(u); v1 += bf_hi(u);
        }
      } else {
        const float2 av = *(const float2*)(aof + ((size_t)row << 7) + 2 * l);
        v0 += av.x; v1 += av.y;
      }
      v0 += bo2.x; v1 += bo2.y;
    }
    const float mean = wredsum(v0 + v1) * (1.f / 128.f);
    const float d0 = v0 - mean, d1 = v1 - mean;
    const float var = wredsum(d0 * d0 + d1 * d1) * (1.f / 128.f);
    const float iv = rsqrtf(var + 1e-3f);
    float h0 = d0 * iv * g12.x + be12.x;
    float h1v = d1 * iv * g12.y + be12.y;
    if (row >= NR){ h0 = 0.f; h1v = 0.f; }
    hreg[i][0] = h0; hreg[i][1] = h1v;
    *(unsigned*)(&FS[lr * 256 + ((4 * l) ^ ((lr & 7) << 4))]) = pk2(h0, h1v);
  }
  __syncthreads();

  const int m = w >> 1, nh = w & 1;
  {
    f32x4 acc1[8];
    #pragma unroll
    for (int nt = 0; nt < 8; ++nt) acc1[nt] = Z4;
    const int arow = 16 * m + c;
    #pragma unroll
    for (int kw = 0; kw < 4; ++kw){
      const s16x8 af = frg(*(const uint4*)(&FS[arow * 256 + ((kw * 64 + a * 16) ^ ((arow & 7) << 4))]));
      #pragma unroll
      for (int nt = 0; nt < 8; ++nt){
        const int j = 128 * nh + 16 * nt + c;
        const s16x8 bf = frg(*(const uint4*)(w1t + j * 128 + kw * 32 + a * 8));
        acc1[nt] = __builtin_amdgcn_mfma_f32_16x16x32_bf16(af, bf, acc1[nt], 0, 0, 0);
      }
    }
    #pragma unroll
    for (int nt = 0; nt < 8; ++nt){
      const int j = 128 * nh + 16 * nt + c;
      const float b1v = b1[j];
      #pragma unroll
      for (int rr = 0; rr < 4; ++rr){
        const int row = 16 * m + 4 * a + rr;
        const float vv = fmaxf(acc1[nt][rr] + b1v, 0.f);
        *(unsigned short*)(&FS[16384 + row * 512 + ((2 * j) ^ ((row & 7) << 4))]) = f2bf(vv);
      }
    }
  }
  __syncthreads();

  {
    f32x4 acc2[4];
    #pragma unroll
    for (int nt = 0; nt < 4; ++nt) acc2[nt] = Z4;
    const int arow = 16 * m + c;
    #pragma unroll
    for (int kw = 0; kw < 8; ++kw){
      const s16x8 af = frg(*(const uint4*)(&FS[16384 + arow * 512 + ((kw * 64 + a * 16) ^ ((arow & 7) << 4))]));
      #pragma unroll
      for (int nt = 0; nt < 4; ++nt){
        const int dd = 64 * nh + 16 * nt + c;
        const s16x8 bf = frg(*(const uint4*)(w2t + dd * 256 + kw * 32 + a * 8));
        acc2[nt] = __builtin_amdgcn_mfma_f32_16x16x32_bf16(af, bf, acc2[nt], 0, 0, 0);
      }
    }
    __syncthreads();
    #pragma unroll
    for (int nt = 0; nt < 4; ++nt){
      const int dd = 64 * nh + 16 * nt + c;
      #pragma unroll
      for (int rr = 0; rr < 4; ++rr){
        const int row = 16 * m + 4 * a + rr;
        *(float*)(&FS[16384 + row * 512 + ((4 * dd) ^ ((row & 4) << 4))]) = acc2[nt][rr];
      }
    }
  }
  __syncthreads();

  const float2 b22  = *(const float2*)(b2  + 2 * l);
  const float2 g22  = *(const float2*)(g2  + 2 * l);
  const float2 be22 = *(const float2*)(be2 + 2 * l);
  int curmb = -1; float s0 = 0.f, s1 = 0.f;
  #pragma unroll 1
  for (int i = 0; i < 8; ++i){
    const int lr = w * 8 + i;
    const int row = rbase + lr;
    if (row >= NR) continue;
    const float2 fv = *(const float2*)(&FS[16384 + lr * 512 + ((8 * l) ^ ((lr & 4) << 4))]);
    const float r0 = hreg[i][0] + fv.x + b22.x;
    const float r1 = hreg[i][1] + fv.y + b22.y;
    const float mean = wredsum(r0 + r1) * (1.f / 128.f);
    const float d0 = r0 - mean, d1 = r1 - mean;
    const float var = wredsum(d0 * d0 + d1 * d1) * (1.f / 128.f);
    const float iv = rsqrtf(var + 1e-3f);
    const float o0 = d0 * iv * g22.x + be22.x;
    const float o1 = d1 * iv * g22.y + be22.y;
    int mb; float wgt;
    if (row < N){ mb = mol[row]; wgt = 1.f; }
    else { mb = row - N; wgt = (float)(160 - (starts[mb + 1] - starts[mb])); }
    if (mb != curmb){
      if (curmb >= 0){
        atomicAdd(&acc[curmb * 128 + 2 * l],     s0);
        atomicAdd(&acc[curmb * 128 + 2 * l + 1], s1);
      }
      curmb = mb; s0 = o0 * wgt; s1 = o1 * wgt;
    } else {
      s0 += o0 * wgt; s1 += o1 * wgt;
    }
  }
  if (curmb >= 0){
    atomicAdd(&acc[curmb * 128 + 2 * l],     s0);
    atomicAdd(&acc[curmb * 128 + 2 * l + 1], s1);
  }
}

// ================= LEGACY (round-2, proven) pipeline for small ws ============
#define LDK 130
__global__ __launch_bounds__(512, 2) void k_attn_v(
    const float* __restrict__ x,
    const float* __restrict__ wq, const float* __restrict__ bq,
    const float* __restrict__ wk, const float* __restrict__ bk,
    const float* __restrict__ wv, const float* __restrict__ bv,
    const float* __restrict__ wo,
    const int* __restrict__ starts, float* __restrict__ ao, int N)
{
  __shared__ unsigned short Qs[161 * LDK];
  __shared__ unsigned short Ks[160 * LDK];
  __shared__ unsigned short Vs[160 * LDK];

  const int b = blockIdx.x >> 3, h = blockIdx.x & 7;
  const int st = starts[b];
  const int n  = starts[b + 1] - st;
  const int nq = n + 1;
  const float* X = x + (size_t)st * 128;
  const int t = threadIdx.x;
  const int k = t & 127, sg = t >> 7;
  const int w = t >> 6,  l = t & 63;

  {
    const float bqv = bq[h * 128 + k], bkv = bk[h * 128 + k], bvv = bv[h * 128 + k];
    const float* wqc = wq + h * 128 + k;
    const float* wkc = wk + h * 128 + k;
    const float* wvc = wv + h * 128 + k;
    const int per = (nq + 3) >> 2;
    const int r0  = sg * per;
    for (int cch = 0; cch < 3; ++cch){
      const int rb = r0 + cch * 16;
      if (rb >= nq) break;
      const float4* xrp[16];
      #pragma unroll
      for (int i = 0; i < 16; ++i){
        int rr = rb + i; int rc = rr < n ? rr : (n - 1);
        xrp[i] = (const float4*)X + (size_t)rc * 32;
      }
      float aq[16], ak[16], av[16];
      #pragma unroll
      for (int i = 0; i < 16; ++i){ aq[i] = bqv; ak[i] = bkv; av[i] = bvv; }
      #pragma unroll 1
      for (int dq = 0; dq < 32; ++dq){
        float4 xv[16];
        #pragma unroll
        for (int i = 0; i < 16; ++i) xv[i] = xrp[i][dq];
        #pragma unroll
        for (int e = 0; e < 4; ++e){
          const int d = dq * 4 + e;
          const float wqv = wqc[d * 1024];
          const float wkv = wkc[d * 1024];
          const float wvv = wvc[d * 1024];
          #pragma unroll
          for (int i = 0; i < 16; ++i){
            const float xs = (e == 0) ? xv[i].x : (e == 1) ? xv[i].y : (e == 2) ? xv[i].z : xv[i].w;
            aq[i] = fmaf(xs, wqv, aq[i]);
            ak[i] = fmaf(xs, wkv, ak[i]);
            av[i] = fmaf(xs, wvv, av[i]);
          }
        }
      }
      #pragma unroll
      for (int i = 0; i < 16; ++i){
        const int rr = rb + i;
        if (rr < n){
          Qs[rr * LDK + k] = f2bf(aq[i]);
          Ks[rr * LDK + k] = f2bf(ak[i]);
          Vs[rr * LDK + k] = f2bf(av[i]);
        } else if (rr == n){
          Qs[rr * LDK + k] = f2bf(bqv);
        }
      }
    }
  }
  __syncthreads();

  const float SCALE = 0.0883883476483184f;
  const int itn = (nq + 7) >> 3;
  for (int it = 0; it < itn; ++it){
    const int sq = w + it * 8;
    if (sq < nq){
      const unsigned* qrow = (const unsigned*)(Qs + sq * LDK);
      const int j0 = l, j1 = l + 64, j2 = l + 128;
      const unsigned* k0r = (const unsigned*)(Ks + j0 * LDK);
      const unsigned* k1r = (const unsigned*)(Ks + j1 * LDK);
      const unsigned* k2r = (const unsigned*)(Ks + (j2 < 160 ? j2 : 159) * LDK);
      float a0 = 0.f, a1 = 0.f, a2 = 0.f;
      #pragma unroll 8
      for (int kk = 0; kk < 64; ++kk){
        const unsigned uq = qrow[kk];
        const float ql = bf_lo(uq), qh = bf_hi(uq);
        const unsigned u0 = k0r[kk], u1 = k1r[kk], u2 = k2r[kk];
        a0 += ql * bf_lo(u0) + qh * bf_hi(u0);
        a1 += ql * bf_lo(u1) + qh * bf_hi(u1);
        a2 += ql * bf_lo(u2) + qh * bf_hi(u2);
      }
      const float s0 = (j0 < n) ? a0 * SCALE : -1e30f;
      const float s1 = (j1 < n) ? a1 * SCALE : -1e30f;
      const float s2 = (j2 < n) ? a2 * SCALE : -1e30f;
      const float m  = wredmax(fmaxf(s0, fmaxf(s1, s2)));
      const float e0 = __expf(s0 - m), e1 = __expf(s1 - m), e2 = __expf(s2 - m);
      const float inv = 1.f / wredsum(e0 + e1 + e2);
      const float p0 = e0 * inv, p1 = e1 * inv, p2 = e2 * inv;
      float o0 = 0.f, o1 = 0.f;
      const unsigned short* vp = Vs + 2 * l;
      #pragma unroll 4
      for (int j = 0; j < 64; ++j){
        const float pj = __shfl(p0, j, 64);
        const unsigned uv = *(const unsigned*)(vp + j * LDK);
        o0 = fmaf(pj, bf_lo(uv), o0);
        o1 = fmaf(pj, bf_hi(uv), o1);
      }
      const int n1 = n < 128 ? n : 128;
      #pragma unroll 4
      for (int j = 64; j < n1; ++j){
        const float pj = __shfl(p1, j - 64, 64);
        const unsigned uv = *(const unsigned*)(vp + j * LDK);
        o0 = fmaf(pj, bf_lo(uv), o0);
        o1 = fmaf(pj, bf_hi(uv), o1);
      }
      #pragma unroll 4
      for (int j = 128; j < n; ++j){
        const float pj = __shfl(p2, j - 128, 64);
        const unsigned uv = *(const unsigned*)(vp + j * LDK);
        o0 = fmaf(pj, bf_lo(uv), o0);
        o1 = fmaf(pj, bf_hi(uv), o1);
      }
      ((unsigned*)(Qs + sq * LDK))[l] = pk2(o0, o1);
    }
  }
  __syncthreads();

  {
    const int d = k;
    const int per = (nq + 3) >> 2;
    const int r0  = sg * per;
    const int rend = min(r0 + per, nq);
    const float* wop = wo + (size_t)(h * 128) * 128 + d;
    for (int cch = 0; cch < 3; ++cch){
      const int rb = r0 + cch * 16;
      if (rb >= rend) break;
      int roff[16];
      #pragma unroll
      for (int i = 0; i < 16; ++i){
        int rr = rb + i;
        roff[i] = (rr < nq ? rr : (nq - 1)) * LDK;
      }
      float acc[16];
      #pragma unroll
      for (int i = 0; i < 16; ++i) acc[i] = 0.f;
      #pragma unroll 1
      for (int kk = 0; kk < 128; ++kk){
        const float wv2 = wop[(size_t)kk * 128];
        #pragma unroll
        for (int i = 0; i < 16; ++i)
          acc[i] = fmaf(bf2f(Qs[roff[i] + kk]), wv2, acc[i]);
      }
      #pragma unroll
      for (int i = 0; i < 16; ++i){
        const int rr = rb + i;
        if (rr < rend){
          const int grow = (rr < n) ? (st + rr) : (N + b);
          atomicAdd(&ao[(size_t)grow * 128 + d], acc[i]);
        }
      }
    }
  }
}

__global__ __launch_bounds__(512, 2) void k_ffn_v(
    const float* __restrict__ x, const int* __restrict__ mol,
    const float* __restrict__ ao, const float* __restrict__ bo,
    const float* __restrict__ w1, const float* __restrict__ b1,
    const float* __restrict__ w2, const float* __restrict__ b2,
    const float* __restrict__ g1, const float* __restrict__ be1,
    const float* __restrict__ g2, const float* __restrict__ be2,
    const int* __restrict__ starts, float* __restrict__ acc,
    int N, int NR)
{
  __shared__ unsigned short Ws[32768];
  __shared__ float h1s[32][128];
  __shared__ unsigned short ts[32][256];
  const int t = threadIdx.x, w = t >> 6, l = t & 63;
  const int rbase = blockIdx.x * 32;

  for (int i = t; i < 32768; i += 512) Ws[i] = f2bf(w1[i]);
  __syncthreads();

  for (int it = 0; it < 4; ++it){
    const int r = w + it * 8;
    const int row = rbase + r;
    if (row < NR){
      float x0 = 0.f, x1 = 0.f;
      if (row < N){
        x0 = x[(size_t)row * 128 + l];
        x1 = x[(size_t)row * 128 + l + 64];
      }
      const float a0 = x0 + ao[(size_t)row * 128 + l]      + bo[l];
      const float a1 = x1 + ao[(size_t)row * 128 + l + 64] + bo[l + 64];
      const float mean = wredsum(a0 + a1) * (1.f / 128.f);
      const float d0 = a0 - mean, d1 = a1 - mean;
      const float var = wredsum(d0 * d0 + d1 * d1) * (1.f / 128.f);
      const float inv = rsqrtf(var + 1e-3f);
      h1s[r][l]      = d0 * inv * g1[l]      + be1[l];
      h1s[r][l + 64] = d1 * inv * g1[l + 64] + be1[l + 64];
    }
    __syncthreads();
    if (row < NR){
      float tj0 = b1[l], tj1 = b1[l + 64], tj2 = b1[l + 128], tj3 = b1[l + 192];
      #pragma unroll 4
      for (int d = 0; d < 128; ++d){
        const float hv = h1s[r][d];
        tj0 = fmaf(hv, bf2f(Ws[d * 256 + l]),       tj0);
        tj1 = fmaf(hv, bf2f(Ws[d * 256 + l + 64]),  tj1);
        tj2 = fmaf(hv, bf2f(Ws[d * 256 + l + 128]), tj2);
        tj3 = fmaf(hv, bf2f(Ws[d * 256 + l + 192]), tj3);
      }
      ts[r][l]       = f2bf(fmaxf(tj0, 0.f));
      ts[r][l + 64]  = f2bf(fmaxf(tj1, 0.f));
      ts[r][l + 128] = f2bf(fmaxf(tj2, 0.f));
      ts[r][l + 192] = f2bf(fmaxf(tj3, 0.f));
    }
  }
  __syncthreads();
  for (int i = t; i < 32768; i += 512) Ws[i] = f2bf(w2[i]);
  __syncthreads();

  for (int it = 0; it < 4; ++it){
    const int r = w + it * 8;
    const int row = rbase + r;
    if (row >= NR) continue;
    float f0 = b2[l], f1 = b2[l + 64];
    #pragma unroll 4
    for (int j = 0; j < 256; ++j){
      const float tv = bf2f(ts[r][j]);
      f0 = fmaf(tv, bf2f(Ws[j * 128 + l]),      f0);
      f1 = fmaf(tv, bf2f(Ws[j * 128 + l + 64]), f1);
    }
    const float r0 = h1s[r][l] + f0, r1 = h1s[r][l + 64] + f1;
    const float mean = wredsum(r0 + r1) * (1.f / 128.f);
    const float d0 = r0 - mean, d1 = r1 - mean;
    const float var = wredsum(d0 * d0 + d1 * d1) * (1.f / 128.f);
    const float inv = rsqrtf(var + 1e-3f);
    const float o0 = d0 * inv * g2[l]      + be2[l];
    const float o1 = d1 * inv * g2[l + 64] + be2[l + 64];
    int mb; float wgt;
    if (row < N){ mb = mol[row]; wgt = 1.f; }
    else { mb = row - N; wgt = (float)(160 - (starts[mb + 1] - starts[mb])); }
    atomicAdd(&acc[mb * 128 + l],      o0 * wgt);
    atomicAdd(&acc[mb * 128 + l + 64], o1 * wgt);
  }
}

// ---------------- kernel D: divide by true atom count ------------------------
__global__ void k_out(const float* __restrict__ acc, const int* __restrict__ starts,
                      float* __restrict__ out){
  const int i = blockIdx.x * blockDim.x + threadIdx.x;
  if (i < 256 * 128){
    const int b = i >> 7;
    out[i] = acc[i] / (float)(starts[b + 1] - starts[b]);
  }
}

extern "C" void kernel_launch(void* const* d_in, const int* in_sizes, int n_in,
                              void* d_out, int out_size, void* d_ws, size_t ws_size,
                              hipStream_t stream)
{
  const float* x   = (const float*)d_in[0];
  const int*   mol = (const int*)d_in[1];
  const float* wq  = (const float*)d_in[2];
  const float* bq  = (const float*)d_in[3];
  const float* wk  = (const float*)d_in[4];
  const float* bk  = (const float*)d_in[5];
  const float* wv  = (const float*)d_in[6];
  const float* bv  = (const float*)d_in[7];
  const float* wo  = (const float*)d_in[8];
  const float* bo  = (const float*)d_in[9];
  const float* w1  = (const float*)d_in[10];
  const float* b1  = (const float*)d_in[11];
  const float* w2  = (const float*)d_in[12];
  const float* b2  = (const float*)d_in[13];
  const float* g1  = (const float*)d_in[14];
  const float* be1 = (const float*)d_in[15];
  const float* g2  = (const float*)d_in[16];
  const float* be2 = (const float*)d_in[17];

  const int N  = in_sizes[1];        // 32706
  const int NR = N + 256;            // + one phantom row per molecule

  const size_t off_wt  = 2048;
  const size_t off_w1t = off_wt  + 1048576;
  const size_t off_w2t = off_w1t + 65536;
  const size_t off_acc = off_w2t + 65536;
  const size_t off_ao  = off_acc + 131072;
  const size_t off_q   = off_ao + (size_t)8 * NR * 128 * 2;
  const size_t need3 = off_q + (size_t)2048 * 45056;        // ~161 MB
  const size_t need2 = off_q;                               // ~68.8 MB
  const size_t need1 = off_ao + (size_t)NR * 128 * 4;       // ~18.2 MB
  const int mode = (ws_size >= need3) ? 3 : (ws_size >= need2) ? 2
                 : (ws_size >= need1) ? 1 : 0;

  char* wsp = (char*)d_ws;
  int* starts = (int*)wsp;

  if (mode >= 1){
    unsigned short* wt  = (unsigned short*)(wsp + off_wt);
    unsigned short* w1t = (unsigned short*)(wsp + off_w1t);
    unsigned short* w2t = (unsigned short*)(wsp + off_w2t);
    float*          acc = (float*)(wsp + off_acc);
    unsigned short* aoh = (unsigned short*)(wsp + off_ao);
    float*          aof = (float*)(wsp + off_ao);
    unsigned short* qg  = (unsigned short*)(wsp + off_q);
    const int useslab = (mode >= 2) ? 1 : 0;

    hipMemsetAsync(acc, 0, 131072, stream);
    if (!useslab) hipMemsetAsync(aof, 0, (size_t)NR * 128 * 4, stream);
    k_prep_all<<<577, 256, 0, stream>>>(wq, wk, wv, wo, w1, w2, mol, N,
                                        wt, w1t, w2t, starts);
    if (mode == 3)
      k_attn3<<<2048, 512, 0, stream>>>(x, wt, bq, bk, bv, starts, aoh, qg, N, NR);
    else
      k_attn<<<2048, 512, 0, stream>>>(x, wt, bq, bk, bv, starts, aoh, aof, useslab, N, NR);
    k_ffn<<<(NR + 63) / 64, 512, 0, stream>>>(x, mol, aoh, aof, useslab, bo, w1t, w2t,
                                              b1, b2, g1, be1, g2, be2, starts, acc, N, NR);
    k_out<<<(256 * 128 + 255) / 256, 256, 0, stream>>>(acc, starts, (float*)d_out);
  } else {
    float* ao  = (float*)(wsp + 2048);
    float* acc = (float*)(wsp + 2048 + (size_t)NR * 128 * 4);
    hipMemsetAsync(ao, 0, (size_t)(NR + 256) * 128 * 4, stream);
    k_starts<<<1, 512, 0, stream>>>(mol, N, starts);
    k_attn_v<<<256 * 8, 512, 0, stream>>>(x, wq, bq, wk, bk, wv, bv, wo, starts, ao, N);
    k_ffn_v<<<(NR + 31) / 32, 512, 0, stream>>>(x, mol, ao, bo, w1, b1, w2, b2,
                                                g1, be1, g2, be2, starts, acc, N, NR);
    k_out<<<(256 * 128 + 255) / 256, 256, 0, stream>>>(acc, starts, (float*)d_out);
  }
}

// Round 21
// 218.128 us; speedup vs baseline: 1.0091x; 1.0091x over previous
//
#include <hip/hip_runtime.h>
#include <hip/hip_bf16.h>

typedef __attribute__((ext_vector_type(8))) short s16x8;
typedef __attribute__((ext_vector_type(4))) float f32x4;

__device__ __forceinline__ float bf_lo(unsigned u){ return __uint_as_float(u << 16); }
__device__ __forceinline__ float bf_hi(unsigned u){ return __uint_as_float(u & 0xFFFF0000u); }
__device__ __forceinline__ unsigned short f2bf(float f){
  unsigned u = __float_as_uint(f);
  u += 0x7FFFu + ((u >> 16) & 1u);
  return (unsigned short)(u >> 16);
}
__device__ __forceinline__ unsigned pk2(float lo, float hi){
  return (unsigned)f2bf(lo) | ((unsigned)f2bf(hi) << 16);
}
__device__ __forceinline__ float bf2f(unsigned short s){ return __uint_as_float(((unsigned)s) << 16); }
__device__ __forceinline__ s16x8 frg(uint4 u){ union { uint4 a; s16x8 b; } x; x.a = u; return x.b; }

#define VX(row) ((((row) & 3) << 4))

__device__ __forceinline__ float wredsum(float v){
  #pragma unroll
  for (int m = 32; m > 0; m >>= 1) v += __shfl_xor(v, m, 64);
  return v;
}
__device__ __forceinline__ float wredmax(float v){
  #pragma unroll
  for (int m = 32; m > 0; m >>= 1) v = fmaxf(v, __shfl_xor(v, m, 64));
  return v;
}

// ---------------- fused prep: starts + all weight transposes ----------------
__global__ void k_prep_all(const float* __restrict__ wq, const float* __restrict__ wk,
                           const float* __restrict__ wv, const float* __restrict__ wo,
                           const float* __restrict__ w1, const float* __restrict__ w2,
                           const int* __restrict__ mol, int N,
                           unsigned short* __restrict__ wt,
                           unsigned short* __restrict__ w1t,
                           unsigned short* __restrict__ w2t,
                           int* __restrict__ starts){
  __shared__ float T[32][33];
  const int bid = blockIdx.x;
  const int t = threadIdx.x;
  if (bid < 512){
    const int mat = bid >> 7, h = (bid >> 4) & 7, tile = bid & 15;
    const int ti = tile >> 2, tj = tile & 3;
    const float* src; int rs;
    if (mat == 0){ src = wq + h * 128; rs = 1024; }
    else if (mat == 1){ src = wk + h * 128; rs = 1024; }
    else if (mat == 2){ src = wv + h * 128; rs = 1024; }
    else { src = wo + h * 16384; rs = 128; }
    for (int i = t; i < 1024; i += 256){
      const int r = i >> 5, cc = i & 31;
      T[r][cc] = src[(size_t)(tj * 32 + r) * rs + ti * 32 + cc];
    }
    __syncthreads();
    unsigned short* dst = wt + ((mat * 8 + h) << 14);
    for (int i = t; i < 1024; i += 256){
      const int orr = i >> 5, occ = i & 31;
      dst[(ti * 32 + orr) * 128 + tj * 32 + occ] = f2bf(T[occ][orr]);
    }
  } else if (bid < 544){
    const int bb = bid - 512;
    const int ti = bb >> 2, tj = bb & 3;
    for (int i = t; i < 1024; i += 256){
      const int r = i >> 5, cc = i & 31;
      T[r][cc] = w1[(size_t)(tj * 32 + r) * 256 + ti * 32 + cc];
    }
    __syncthreads();
    for (int i = t; i < 1024; i += 256){
      const int orr = i >> 5, occ = i & 31;
      w1t[(ti * 32 + orr) * 128 + tj * 32 + occ] = f2bf(T[occ][orr]);
    }
  } else if (bid < 576){
    const int bb = bid - 544;
    const int ti = bb >> 3, tj = bb & 7;
    for (int i = t; i < 1024; i += 256){
      const int r = i >> 5, cc = i & 31;
      T[r][cc] = w2[(size_t)(tj * 32 + r) * 128 + ti * 32 + cc];
    }
    __syncthreads();
    for (int i = t; i < 1024; i += 256){
      const int orr = i >> 5, occ = i & 31;
      w2t[(ti * 32 + orr) * 256 + tj * 32 + occ] = f2bf(T[occ][orr]);
    }
  } else {
    for (int i = t; i <= 256; i += 256){
      int lo = 0, hi = N;
      while (lo < hi){ const int m = (lo + hi) >> 1; if (mol[m] < i) lo = m + 1; else hi = m; }
      starts[i] = lo;
    }
  }
}

// legacy standalone starts (mode 0)
__global__ void k_starts(const int* __restrict__ mol, int N, int* __restrict__ starts){
  const int t = blockIdx.x * blockDim.x + threadIdx.x;
  if (t <= 256){
    int lo = 0, hi = N;
    while (lo < hi){ const int m = (lo + hi) >> 1; if (mol[m] < t) lo = m + 1; else hi = m; }
    starts[t] = lo;
  }
}

// softmax over S[10] -> normalized bf16 P[10] (pairs packed in uint2)
#define SM2P(Sx, Pd) do { \
    float mx = -3.0e38f; \
    _Pragma("unroll") \
    for (int kt = 0; kt < 10; ++kt) if (kt < KTn){ \
      _Pragma("unroll") \
      for (int r = 0; r < 4; ++r){ \
        const int key = 16 * kt + 4 * a + r; \
        const float sv = (key < n) ? Sx[kt][r] * SCALE : -1.0e30f; \
        Sx[kt][r] = sv; mx = fmaxf(mx, sv); \
      } \
    } \
    mx = fmaxf(mx, __shfl_xor(mx, 16, 64)); \
    mx = fmaxf(mx, __shfl_xor(mx, 32, 64)); \
    float sum = 0.f; \
    _Pragma("unroll") \
    for (int kt = 0; kt < 10; ++kt) if (kt < KTn){ \
      _Pragma("unroll") \
      for (int r = 0; r < 4; ++r){ \
        const float e = __expf(Sx[kt][r] - mx); \
        Sx[kt][r] = e; sum += e; \
      } \
    } \
    sum += __shfl_xor(sum, 16, 64); \
    sum += __shfl_xor(sum, 32, 64); \
    const float inv = 1.f / sum; \
    _Pragma("unroll") \
    for (int kt = 0; kt < 10; ++kt) if (kt < KTn){ \
      uint2 u; \
      u.x = pk2(Sx[kt][0] * inv, Sx[kt][1] * inv); \
      u.y = pk2(Sx[kt][2] * inv, Sx[kt][3] * inv); \
      Pd[kt] = u; \
    } \
  } while(0)

// ---------------- kernel B3: 80KB-LDS attention, 2 blocks/CU ----------------
// r21 = r18 exact restore (best: 218.3us total). r19 AO dual-pass fusion was
// neutral-negative (reverted); r20 restore dropped k_attn (compile fail).
// Assoc fusion AO=P·(V·Wo) + dual-q S-phase fusion. Proven optimum.
// LDS [0,40960): X rows -> K rows (bar2) -> 8 P slabs (bar5)
//     [40960,81920): V rows [key][dv] (256B, K-swz) -> VW^T [d][k] (320B, VX)
// Q round-trips global in blocked B-frag layout (45056 B/block).
// NOTE negatives: cvt_pk asm(r6), setprio(r6), 1024thr(r8 spill),
// dual-q@1blk(r10), XCD remap(r14), AO dual-pass fusion(r19).
__global__ __launch_bounds__(512, 4) void k_attn3(
    const float* __restrict__ x, const unsigned short* __restrict__ wt,
    const float* __restrict__ bqg, const float* __restrict__ bkg, const float* __restrict__ bvg,
    const int* __restrict__ starts,
    unsigned short* __restrict__ aoh, unsigned short* __restrict__ qg, int N, int NR)
{
  __shared__ unsigned char SH[81920];
  const int bid = blockIdx.x;
  const int b = bid >> 3, h = bid & 7;
  const int st = starts[b];
  const int n  = starts[b + 1] - st;        // 96..160
  const int KTn = (n + 15) >> 4;
  const int QTn = (n + 16) >> 4;
  const int t = threadIdx.x, w = t >> 6, l = t & 63;
  const int c = l & 15, a = l >> 4;
  const f32x4 Z4 = {0.f, 0.f, 0.f, 0.f};
  unsigned char* Qg = (unsigned char*)qg + (size_t)bid * 45056;

  // ---- stage X (region A) ----
  for (int i = t; i < 5120; i += 512){
    const int r = i >> 5, c4 = i & 31;
    uint2 v; v.x = 0u; v.y = 0u;
    if (r < n){
      const float4 xv = *(const float4*)(x + ((size_t)(st + r) << 7) + (c4 << 2));
      v.x = pk2(xv.x, xv.y); v.y = pk2(xv.z, xv.w);
    }
    *(uint2*)(&SH[r * 256 + ((c4 * 8) ^ ((r & 7) << 4))]) = v;
  }
  __syncthreads();                                    // bar1

  const unsigned short* wqt = wt + ((0 * 8 + h) << 14);
  const unsigned short* wkt = wt + ((1 * 8 + h) << 14);
  const unsigned short* wvt = wt + ((2 * 8 + h) << 14);
  const unsigned short* wot = wt + ((3 * 8 + h) << 14);

  // ---- Q proj -> global blocked layout ----
  {
    f32x4 CQ[11];
    #pragma unroll
    for (int qt = 0; qt < 11; ++qt) CQ[qt] = Z4;
    #pragma unroll
    for (int kw = 0; kw < 4; ++kw){
      const s16x8 aq = frg(*(const uint4*)(wqt + (16 * w + c) * 128 + kw * 32 + a * 8));
      #pragma unroll
      for (int qt = 0; qt < 11; ++qt) if (qt < QTn){
        const int r0 = 16 * qt + c;
        const int row = r0 < 160 ? r0 : 159;
        const s16x8 xf = frg(*(const uint4*)(&SH[row * 256 + ((kw * 64 + a * 16) ^ ((row & 7) << 4))]));
        CQ[qt] = __builtin_amdgcn_mfma_f32_16x16x32_bf16(aq, xf, CQ[qt], 0, 0, 0);
      }
    }
    const float4 bq4 = *(const float4*)(bqg + h * 128 + 16 * w + 4 * a);
    const int kwq = w >> 1, ksq = 2 * (w & 1) + (a >> 1), half = a & 1;
    #pragma unroll
    for (int qt = 0; qt < 11; ++qt) if (qt < QTn){
      uint2 u;
      u.x = pk2(CQ[qt][0] + bq4.x, CQ[qt][1] + bq4.y);
      u.y = pk2(CQ[qt][2] + bq4.z, CQ[qt][3] + bq4.w);
      *(uint2*)(Qg + ((((qt * 4 + kwq) * 4 + ksq) * 16 + c) << 4) + 8 * half) = u;
    }
  }
  // ---- fused K+V projection: ONE X-read feeds both MFMAs ----
  {
    f32x4 CK[10], CV[10];
    #pragma unroll
    for (int kt = 0; kt < 10; ++kt){ CK[kt] = Z4; CV[kt] = Z4; }
    #pragma unroll
    for (int kw = 0; kw < 4; ++kw){
      const int wofs = (16 * w + c) * 128 + kw * 32 + a * 8;
      const s16x8 ak  = frg(*(const uint4*)(wkt + wofs));
      const s16x8 bv8 = frg(*(const uint4*)(wvt + wofs));
      #pragma unroll
      for (int kt = 0; kt < 10; ++kt) if (kt < KTn){
        const int row = 16 * kt + c;
        const s16x8 xf = frg(*(const uint4*)(&SH[row * 256 + ((kw * 64 + a * 16) ^ ((row & 7) << 4))]));
        CK[kt] = __builtin_amdgcn_mfma_f32_16x16x32_bf16(ak, xf, CK[kt], 0, 0, 0);
        CV[kt] = __builtin_amdgcn_mfma_f32_16x16x32_bf16(xf, bv8, CV[kt], 0, 0, 0);
      }
    }
    // V -> region B ROW-MAJOR [key][dv], stride 256, K-style swizzle.
    const float bvv = bvg[h * 128 + 16 * w + c];
    #pragma unroll
    for (int kt = 0; kt < 10; ++kt) if (kt < KTn){
      #pragma unroll
      for (int r = 0; r < 4; ++r){
        const int key = 16 * kt + 4 * a + r;
        *(unsigned short*)(&SH[40960 + key * 256 +
            ((((16 * w + c) << 1)) ^ ((key & 7) << 4))]) = f2bf(CV[kt][r] + bvv);
      }
    }
    __syncthreads();                                  // bar2: all X reads done
    const float4 bk4 = *(const float4*)(bkg + h * 128 + 16 * w + 4 * a);
    #pragma unroll
    for (int kt = 0; kt < 10; ++kt) if (kt < KTn){
      const int key = 16 * kt + c;
      uint2 u;
      u.x = pk2(CK[kt][0] + bk4.x, CK[kt][1] + bk4.y);
      u.y = pk2(CK[kt][2] + bk4.z, CK[kt][3] + bk4.w);
      *(uint2*)(&SH[key * 256 + ((32 * w + 8 * a) ^ ((key & 7) << 4))]) = u;
    }
  }
  __syncthreads();                                    // bar3: K + V ready

  // ---- S + softmax; dual-q fused when both tiles exist ----
  const float SCALE = 0.08838834764831845f;
  uint2 P[2][10];
  {
    const int qt0 = w, qt1 = w + 8;
    if (qt0 < QTn){
      if (qt1 < QTn){
        // dual: q0 = 16*qt0+c <= 127 (w<=2 here) -> no phantom patch on bu0
        const int q1 = 16 * qt1 + c;
        f32x4 Sa[10], Sb[10];
        #pragma unroll
        for (int kt = 0; kt < 10; ++kt){ Sa[kt] = Z4; Sb[kt] = Z4; }
        #pragma unroll
        for (int kw = 0; kw < 4; ++kw){
          const uint4 bu0 = *(const uint4*)(Qg + ((((qt0 * 4 + kw) * 4 + a) * 16 + c) << 4));
          uint4 bu1 = *(const uint4*)(Qg + ((((qt1 * 4 + kw) * 4 + a) * 16 + c) << 4));
          if (q1 == 160){
            const float4 p0 = *(const float4*)(bqg + h * 128 + kw * 32 + 8 * a);
            const float4 p1 = *(const float4*)(bqg + h * 128 + kw * 32 + 8 * a + 4);
            bu1.x = pk2(p0.x, p0.y); bu1.y = pk2(p0.z, p0.w);
            bu1.z = pk2(p1.x, p1.y); bu1.w = pk2(p1.z, p1.w);
          }
          const s16x8 qa = frg(bu0);
          const s16x8 qb = frg(bu1);
          #pragma unroll
          for (int kt = 0; kt < 10; ++kt) if (kt < KTn){
            const int krow = 16 * kt + c;
            const s16x8 kf = frg(*(const uint4*)(&SH[krow * 256 + ((kw * 64 + a * 16) ^ ((krow & 7) << 4))]));
            Sa[kt] = __builtin_amdgcn_mfma_f32_16x16x32_bf16(kf, qa, Sa[kt], 0, 0, 0);
            Sb[kt] = __builtin_amdgcn_mfma_f32_16x16x32_bf16(kf, qb, Sb[kt], 0, 0, 0);
          }
        }
        SM2P(Sa, P[0]);
        SM2P(Sb, P[1]);
      } else {
        // single: q0 <= 127 -> no phantom patch needed
        f32x4 Sa[10];
        #pragma unroll
        for (int kt = 0; kt < 10; ++kt) Sa[kt] = Z4;
        #pragma unroll
        for (int kw = 0; kw < 4; ++kw){
          const uint4 bu0 = *(const uint4*)(Qg + ((((qt0 * 4 + kw) * 4 + a) * 16 + c) << 4));
          const s16x8 qa = frg(bu0);
          #pragma unroll
          for (int kt = 0; kt < 10; ++kt) if (kt < KTn){
            const int krow = 16 * kt + c;
            const s16x8 kf = frg(*(const uint4*)(&SH[krow * 256 + ((kw * 64 + a * 16) ^ ((krow & 7) << 4))]));
            Sa[kt] = __builtin_amdgcn_mfma_f32_16x16x32_bf16(kf, qa, Sa[kt], 0, 0, 0);
          }
        }
        SM2P(Sa, P[0]);
      }
    }
  }

  // ---- VW = V · Wo_h : wave w owns d-tile w (C[key][d], 40 MFMAs) ----
  f32x4 CW[10];
  #pragma unroll
  for (int kt = 0; kt < 10; ++kt) CW[kt] = Z4;
  #pragma unroll
  for (int kw = 0; kw < 4; ++kw){
    const s16x8 wf = frg(*(const uint4*)(wot + (16 * w + c) * 128 + kw * 32 + a * 8));
    #pragma unroll
    for (int kt = 0; kt < 10; ++kt) if (kt < KTn){
      const int row = 16 * kt + c;
      const s16x8 vf = frg(*(const uint4*)(&SH[40960 + row * 256 + ((kw * 64 + a * 16) ^ ((row & 7) << 4))]));
      CW[kt] = __builtin_amdgcn_mfma_f32_16x16x32_bf16(vf, wf, CW[kt], 0, 0, 0);
    }
  }
  __syncthreads();                                    // bar4: V reads done, K dead

  // store VW^T [d][k] stride 320, VX swizzle over region B
  #pragma unroll
  for (int kt = 0; kt < 10; ++kt) if (kt < KTn){
    uint2 u;
    u.x = pk2(CW[kt][0], CW[kt][1]);
    u.y = pk2(CW[kt][2], CW[kt][3]);
    *(uint2*)(&SH[40960 + (16 * w + c) * 320 + ((((16 * kt + 4 * a) << 1)) ^ VX(c))]) = u;
  }
  // pad-zero the VW^T tail key-tile when KTn odd (r17 NaN fix)
  if (KTn & 1){
    uint2 z; z.x = 0u; z.y = 0u;
    *(uint2*)(&SH[40960 + (16 * w + c) * 320 + ((((16 * KTn + 4 * a) << 1)) ^ VX(c))]) = z;
  }
  __syncthreads();                                    // bar5: VW^T ready, slabs free

  // ---- per-pass: P->slab, AO = P·VW directly, store ----
  const int pb = w * 5120;
  const int kwn = (KTn + 1) >> 1;
  #pragma unroll
  for (int pass = 0; pass < 2; ++pass){
    const int qt = w + 8 * pass;
    if (qt < QTn){
      const int q = 16 * qt + c;
      #pragma unroll
      for (int kt = 0; kt < 10; ++kt) if (kt < KTn)
        *(uint2*)(&SH[pb + c * 320 + ((((16 * kt + 4 * a) << 1)) ^ VX(c))]) = P[pass][kt];
      if (KTn & 1){
        uint2 z; z.x = 0u; z.y = 0u;
        *(uint2*)(&SH[pb + c * 320 + ((((16 * KTn + 4 * a) << 1)) ^ VX(c))]) = z;
      }
      f32x4 AO[8];
      #pragma unroll
      for (int dt = 0; dt < 8; ++dt) AO[dt] = Z4;
      for (int k2 = 0; k2 < kwn; ++k2){
        const s16x8 pf = frg(*(const uint4*)(&SH[pb + c * 320 + ((k2 * 64 + a * 16) ^ VX(c))]));
        #pragma unroll
        for (int dt = 0; dt < 8; ++dt){
          const s16x8 vwf = frg(*(const uint4*)(&SH[40960 + (16 * dt + c) * 320 + ((k2 * 64 + a * 16) ^ VX(c))]));
          AO[dt] = __builtin_amdgcn_mfma_f32_16x16x32_bf16(vwf, pf, AO[dt], 0, 0, 0);
        }
      }
      if (q <= n){
        const int grow = (q < n) ? (st + q) : (N + b);
        unsigned short* dst = aoh + (((size_t)h * NR + grow) << 7);
        #pragma unroll
        for (int dt = 0; dt < 8; ++dt){
          uint2 u; u.x = pk2(AO[dt][0], AO[dt][1]); u.y = pk2(AO[dt][2], AO[dt][3]);
          *(uint2*)(dst + 16 * dt + 4 * a) = u;
        }
      }
    }
  }
}

// ---------------- kernel B: round-9 proven attention (mode 1/2 fallback) ----
__global__ __launch_bounds__(512, 2) void k_attn(
    const float* __restrict__ x, const unsigned short* __restrict__ wt,
    const float* __restrict__ bqg, const float* __restrict__ bkg, const float* __restrict__ bvg,
    const int* __restrict__ starts,
    unsigned short* aoh, float* aof, int useslab, int N, int NR)
{
  __shared__ unsigned char SH[163840];
  const int b = blockIdx.x >> 3, h = blockIdx.x & 7;
  const int st = starts[b];
  const int n  = starts[b + 1] - st;
  const int KTn = (n + 15) >> 4;
  const int QTn = (n + 16) >> 4;
  const int t = threadIdx.x, w = t >> 6, l = t & 63;
  const int c = l & 15, a = l >> 4;
  const f32x4 Z4 = {0.f, 0.f, 0.f, 0.f};

  for (int i = t; i < 5120; i += 512){
    const int r = i >> 5, c4 = i & 31;
    uint2 v; v.x = 0u; v.y = 0u;
    if (r < n){
      const float4 xv = *(const float4*)(x + ((size_t)(st + r) << 7) + (c4 << 2));
      v.x = pk2(xv.x, xv.y); v.y = pk2(xv.z, xv.w);
    }
    *(uint2*)(&SH[r * 256 + ((c4 * 8) ^ ((r & 7) << 4))]) = v;
  }
  if (KTn & 1){
    const int dv = t >> 2, kq = t & 3;
    uint2 z; z.x = 0u; z.y = 0u;
    if (dv < 128) *(uint2*)(&SH[81920 + dv * 320 + ((KTn * 32 + kq * 8) ^ VX(dv))]) = z;
  }
  __syncthreads();

  const unsigned short* wqt = wt + ((0 * 8 + h) << 14);
  const unsigned short* wkt = wt + ((1 * 8 + h) << 14);
  const unsigned short* wvt = wt + ((2 * 8 + h) << 14);
  const unsigned short* wot = wt + ((3 * 8 + h) << 14);

  {
    f32x4 CK[10], CV[10];
    #pragma unroll
    for (int kt = 0; kt < 10; ++kt){ CK[kt] = Z4; CV[kt] = Z4; }
    #pragma unroll
    for (int kw = 0; kw < 4; ++kw){
      const int wofs = (16 * w + c) * 128 + kw * 32 + a * 8;
      const s16x8 ak  = frg(*(const uint4*)(wkt + wofs));
      const s16x8 bv8 = frg(*(const uint4*)(wvt + wofs));
      #pragma unroll
      for (int kt = 0; kt < 10; ++kt) if (kt < KTn){
        const int row = 16 * kt + c;
        const s16x8 xf = frg(*(const uint4*)(&SH[row * 256 + ((kw * 64 + a * 16) ^ ((row & 7) << 4))]));
        CK[kt] = __builtin_amdgcn_mfma_f32_16x16x32_bf16(ak, xf, CK[kt], 0, 0, 0);
        CV[kt] = __builtin_amdgcn_mfma_f32_16x16x32_bf16(xf, bv8, CV[kt], 0, 0, 0);
      }
    }
    const float4 bk4 = *(const float4*)(bkg + h * 128 + 16 * w + 4 * a);
    const float  bvv = bvg[h * 128 + 16 * w + c];
    #pragma unroll
    for (int kt = 0; kt < 10; ++kt) if (kt < KTn){
      const int key = 16 * kt + c;
      uint2 u;
      u.x = pk2(CK[kt][0] + bk4.x, CK[kt][1] + bk4.y);
      u.y = pk2(CK[kt][2] + bk4.z, CK[kt][3] + bk4.w);
      *(uint2*)(&SH[40960 + key * 256 + ((32 * w + 8 * a) ^ ((key & 7) << 4))]) = u;
      uint2 v;
      v.x = pk2(CV[kt][0] + bvv, CV[kt][1] + bvv);
      v.y = pk2(CV[kt][2] + bvv, CV[kt][3] + bvv);
      *(uint2*)(&SH[81920 + (16 * w + c) * 320 + ((((16 * kt + 4 * a) << 1)) ^ VX(c))]) = v;
    }
  }
  {
    f32x4 CQ[11];
    #pragma unroll
    for (int qt = 0; qt < 11; ++qt) CQ[qt] = Z4;
    #pragma unroll
    for (int kw = 0; kw < 4; ++kw){
      const s16x8 aq = frg(*(const uint4*)(wqt + (16 * w + c) * 128 + kw * 32 + a * 8));
      #pragma unroll
      for (int qt = 0; qt < 11; ++qt) if (qt < QTn){
        const int r0 = 16 * qt + c;
        const int row = r0 < 160 ? r0 : 159;
        const s16x8 xf = frg(*(const uint4*)(&SH[row * 256 + ((kw * 64 + a * 16) ^ ((row & 7) << 4))]));
        CQ[qt] = __builtin_amdgcn_mfma_f32_16x16x32_bf16(aq, xf, CQ[qt], 0, 0, 0);
      }
    }
    __syncthreads();
    const float4 bq4 = *(const float4*)(bqg + h * 128 + 16 * w + 4 * a);
    #pragma unroll
    for (int qt = 0; qt < 11; ++qt) if (qt < QTn){
      const int q = 16 * qt + c;
      if (q < 160){
        uint2 u;
        u.x = pk2(CQ[qt][0] + bq4.x, CQ[qt][1] + bq4.y);
        u.y = pk2(CQ[qt][2] + bq4.z, CQ[qt][3] + bq4.w);
        *(uint2*)(&SH[q * 256 + ((32 * w + 8 * a) ^ ((q & 7) << 4))]) = u;
      }
    }
  }
  __syncthreads();

  const float SCALE = 0.08838834764831845f;
  const int pb = 122880 + w * 5120;
  for (int qt = w; qt < QTn; qt += 8){
    const int q = 16 * qt + c;
    f32x4 S[10];
    #pragma unroll
    for (int kt = 0; kt < 10; ++kt) S[kt] = Z4;
    #pragma unroll
    for (int kw = 0; kw < 4; ++kw){
      const int qrow = q < 160 ? q : 159;
      uint4 bu = *(const uint4*)(&SH[qrow * 256 + ((kw * 64 + a * 16) ^ ((qrow & 7) << 4))]);
      if (q == 160){
        const float4 p0 = *(const float4*)(bqg + h * 128 + kw * 32 + a * 8);
        const float4 p1 = *(const float4*)(bqg + h * 128 + kw * 32 + a * 8 + 4);
        bu.x = pk2(p0.x, p0.y); bu.y = pk2(p0.z, p0.w);
        bu.z = pk2(p1.x, p1.y); bu.w = pk2(p1.z, p1.w);
      }
      const s16x8 qb = frg(bu);
      #pragma unroll
      for (int kt = 0; kt < 10; ++kt) if (kt < KTn){
        const int krow = 16 * kt + c;
        const s16x8 kf = frg(*(const uint4*)(&SH[40960 + krow * 256 + ((kw * 64 + a * 16) ^ ((krow & 7) << 4))]));
        S[kt] = __builtin_amdgcn_mfma_f32_16x16x32_bf16(kf, qb, S[kt], 0, 0, 0);
      }
    }
    float mx = -3.0e38f;
    #pragma unroll
    for (int kt = 0; kt < 10; ++kt) if (kt < KTn){
      #pragma unroll
      for (int r = 0; r < 4; ++r){
        const int key = 16 * kt + 4 * a + r;
        const float sv = (key < n) ? S[kt][r] * SCALE : -1.0e30f;
        S[kt][r] = sv; mx = fmaxf(mx, sv);
      }
    }
    mx = fmaxf(mx, __shfl_xor(mx, 16, 64));
    mx = fmaxf(mx, __shfl_xor(mx, 32, 64));
    float sum = 0.f;
    #pragma unroll
    for (int kt = 0; kt < 10; ++kt) if (kt < KTn){
      #pragma unroll
      for (int r = 0; r < 4; ++r){
        const float e = __expf(S[kt][r] - mx);
        S[kt][r] = e; sum += e;
      }
    }
    sum += __shfl_xor(sum, 16, 64);
    sum += __shfl_xor(sum, 32, 64);
    const float inv = 1.f / sum;
    #pragma unroll
    for (int kt = 0; kt < 10; ++kt) if (kt < KTn){
      uint2 u;
      u.x = pk2(S[kt][0] * inv, S[kt][1] * inv);
      u.y = pk2(S[kt][2] * inv, S[kt][3] * inv);
      *(uint2*)(&SH[pb + c * 320 + ((((16 * kt + 4 * a) << 1)) ^ VX(c))]) = u;
    }
    if (KTn & 1){
      uint2 z; z.x = 0u; z.y = 0u;
      *(uint2*)(&SH[pb + c * 320 + ((((16 * KTn + 4 * a) << 1)) ^ VX(c))]) = z;
    }
    f32x4 O[8];
    #pragma unroll
    for (int dt = 0; dt < 8; ++dt) O[dt] = Z4;
    const int kwn = (KTn + 1) >> 1;
    for (int k2 = 0; k2 < kwn; ++k2){
      const s16x8 pf = frg(*(const uint4*)(&SH[pb + c * 320 + ((k2 * 64 + a * 16) ^ VX(c))]));
      #pragma unroll
      for (int dt = 0; dt < 8; ++dt){
        const s16x8 vf = frg(*(const uint4*)(&SH[81920 + (16 * dt + c) * 320 + ((k2 * 64 + a * 16) ^ VX(c))]));
        O[dt] = __builtin_amdgcn_mfma_f32_16x16x32_bf16(vf, pf, O[dt], 0, 0, 0);
      }
    }
    #pragma unroll
    for (int dt = 0; dt < 8; ++dt){
      uint2 u; u.x = pk2(O[dt][0], O[dt][1]); u.y = pk2(O[dt][2], O[dt][3]);
      *(uint2*)(&SH[pb + c * 320 + ((((16 * dt + 4 * a) << 1)) ^ VX(c))]) = u;
    }
    f32x4 AO[8];
    #pragma unroll
    for (int dt = 0; dt < 8; ++dt) AO[dt] = Z4;
    #pragma unroll
    for (int kw = 0; kw < 4; ++kw){
      const s16x8 ob = frg(*(const uint4*)(&SH[pb + c * 320 + ((kw * 64 + a * 16) ^ VX(c))]));
      #pragma unroll
      for (int dt = 0; dt < 8; ++dt){
        const s16x8 wf = frg(*(const uint4*)(wot + (16 * dt + c) * 128 + kw * 32 + a * 8));
        AO[dt] = __builtin_amdgcn_mfma_f32_16x16x32_bf16(wf, ob, AO[dt], 0, 0, 0);
      }
    }
    if (q <= n){
      const int grow = (q < n) ? (st + q) : (N + b);
      if (useslab){
        unsigned short* dst = aoh + (((size_t)h * NR + grow) << 7);
        #pragma unroll
        for (int dt = 0; dt < 8; ++dt){
          uint2 u; u.x = pk2(AO[dt][0], AO[dt][1]); u.y = pk2(AO[dt][2], AO[dt][3]);
          *(uint2*)(dst + 16 * dt + 4 * a) = u;
        }
      } else {
        float* dstf = aof + ((size_t)grow << 7);
        #pragma unroll
        for (int dt = 0; dt < 8; ++dt){
          #pragma unroll
          for (int r = 0; r < 4; ++r)
            atomicAdd(dstf + 16 * dt + 4 * a + r, AO[dt][r]);
        }
      }
    }
  }
}

// ---------------- kernel C: MFMA residual+LN1+FFN+LN2+readout ----------------
__global__ __launch_bounds__(512, 4) void k_ffn(
    const float* __restrict__ x, const int* __restrict__ mol,
    const unsigned short* aoh, const float* aof, int useslab,
    const float* __restrict__ bo,
    const unsigned short* __restrict__ w1t, const unsigned short* __restrict__ w2t,
    const float* __restrict__ b1, const float* __restrict__ b2,
    const float* __restrict__ g1, const float* __restrict__ be1,
    const float* __restrict__ g2, const float* __restrict__ be2,
    const int* __restrict__ starts, float* __restrict__ acc,
    int N, int NR)
{
  __shared__ unsigned char FS[49152];
  const int t = threadIdx.x, w = t >> 6, l = t & 63;
  const int c = l & 15, a = l >> 4;
  const int rbase = blockIdx.x * 64;
  const f32x4 Z4 = {0.f, 0.f, 0.f, 0.f};

  const float2 bo2  = *(const float2*)(bo  + 2 * l);
  const float2 g12  = *(const float2*)(g1  + 2 * l);
  const float2 be12 = *(const float2*)(be1 + 2 * l);

  float hreg[8][2];

  #pragma unroll 1
  for (int i = 0; i < 8; ++i){
    const int lr = w * 8 + i;
    const int row = rbase + lr;
    float v0 = 0.f, v1 = 0.f;
    if (row < NR){
      if (row < N){
        const float2 xv = *(const float2*)(x + ((size_t)row << 7) + 2 * l);
        v0 = xv.x; v1 = xv.y;
      }
      if (useslab){
        #pragma unroll
        for (int hh = 0; hh < 8; ++hh){
          const unsigned u = *(const unsigned*)(aoh + (((size_t)hh * NR + row) << 7) + 2 * l);
          v0 += bf_lo(u); v1 += bf_hi(u);
        }
      } else {
        const float2 av = *(const float2*)(aof + ((size_t)row << 7) + 2 * l);
        v0 += av.x; v1 += av.y;
      }
      v0 += bo2.x; v1 += bo2.y;
    }
    const float mean = wredsum(v0 + v1) * (1.f / 128.f);
    const float d0 = v0 - mean, d1 = v1 - mean;
    const float var = wredsum(d0 * d0 + d1 * d1) * (1.f / 128.f);
    const float iv = rsqrtf(var + 1e-3f);
    float h0 = d0 * iv * g12.x + be12.x;
    float h1v = d1 * iv * g12.y + be12.y;
    if (row >= NR){ h0 = 0.f; h1v = 0.f; }
    hreg[i][0] = h0; hreg[i][1] = h1v;
    *(unsigned*)(&FS[lr * 256 + ((4 * l) ^ ((lr & 7) << 4))]) = pk2(h0, h1v);
  }
  __syncthreads();

  const int m = w >> 1, nh = w & 1;
  {
    f32x4 acc1[8];
    #pragma unroll
    for (int nt = 0; nt < 8; ++nt) acc1[nt] = Z4;
    const int arow = 16 * m + c;
    #pragma unroll
    for (int kw = 0; kw < 4; ++kw){
      const s16x8 af = frg(*(const uint4*)(&FS[arow * 256 + ((kw * 64 + a * 16) ^ ((arow & 7) << 4))]));
      #pragma unroll
      for (int nt = 0; nt < 8; ++nt){
        const int j = 128 * nh + 16 * nt + c;
        const s16x8 bf = frg(*(const uint4*)(w1t + j * 128 + kw * 32 + a * 8));
        acc1[nt] = __builtin_amdgcn_mfma_f32_16x16x32_bf16(af, bf, acc1[nt], 0, 0, 0);
      }
    }
    #pragma unroll
    for (int nt = 0; nt < 8; ++nt){
      const int j = 128 * nh + 16 * nt + c;
      const float b1v = b1[j];
      #pragma unroll
      for (int rr = 0; rr < 4; ++rr){
        const int row = 16 * m + 4 * a + rr;
        const float vv = fmaxf(acc1[nt][rr] + b1v, 0.f);
        *(unsigned short*)(&FS[16384 + row * 512 + ((2 * j) ^ ((row & 7) << 4))]) = f2bf(vv);
      }
    }
  }
  __syncthreads();

  {
    f32x4 acc2[4];
    #pragma unroll
    for (int nt = 0; nt < 4; ++nt) acc2[nt] = Z4;
    const int arow = 16 * m + c;
    #pragma unroll
    for (int kw = 0; kw < 8; ++kw){
      const s16x8 af = frg(*(const uint4*)(&FS[16384 + arow * 512 + ((kw * 64 + a * 16) ^ ((arow & 7) << 4))]));
      #pragma unroll
      for (int nt = 0; nt < 4; ++nt){
        const int dd = 64 * nh + 16 * nt + c;
        const s16x8 bf = frg(*(const uint4*)(w2t + dd * 256 + kw * 32 + a * 8));
        acc2[nt] = __builtin_amdgcn_mfma_f32_16x16x32_bf16(af, bf, acc2[nt], 0, 0, 0);
      }
    }
    __syncthreads();
    #pragma unroll
    for (int nt = 0; nt < 4; ++nt){
      const int dd = 64 * nh + 16 * nt + c;
      #pragma unroll
      for (int rr = 0; rr < 4; ++rr){
        const int row = 16 * m + 4 * a + rr;
        *(float*)(&FS[16384 + row * 512 + ((4 * dd) ^ ((row & 4) << 4))]) = acc2[nt][rr];
      }
    }
  }
  __syncthreads();

  const float2 b22  = *(const float2*)(b2  + 2 * l);
  const float2 g22  = *(const float2*)(g2  + 2 * l);
  const float2 be22 = *(const float2*)(be2 + 2 * l);
  int curmb = -1; float s0 = 0.f, s1 = 0.f;
  #pragma unroll 1
  for (int i = 0; i < 8; ++i){
    const int lr = w * 8 + i;
    const int row = rbase + lr;
    if (row >= NR) continue;
    const float2 fv = *(const float2*)(&FS[16384 + lr * 512 + ((8 * l) ^ ((lr & 4) << 4))]);
    const float r0 = hreg[i][0] + fv.x + b22.x;
    const float r1 = hreg[i][1] + fv.y + b22.y;
    const float mean = wredsum(r0 + r1) * (1.f / 128.f);
    const float d0 = r0 - mean, d1 = r1 - mean;
    const float var = wredsum(d0 * d0 + d1 * d1) * (1.f / 128.f);
    const float iv = rsqrtf(var + 1e-3f);
    const float o0 = d0 * iv * g22.x + be22.x;
    const float o1 = d1 * iv * g22.y + be22.y;
    int mb; float wgt;
    if (row < N){ mb = mol[row]; wgt = 1.f; }
    else { mb = row - N; wgt = (float)(160 - (starts[mb + 1] - starts[mb])); }
    if (mb != curmb){
      if (curmb >= 0){
        atomicAdd(&acc[curmb * 128 + 2 * l],     s0);
        atomicAdd(&acc[curmb * 128 + 2 * l + 1], s1);
      }
      curmb = mb; s0 = o0 * wgt; s1 = o1 * wgt;
    } else {
      s0 += o0 * wgt; s1 += o1 * wgt;
    }
  }
  if (curmb >= 0){
    atomicAdd(&acc[curmb * 128 + 2 * l],     s0);
    atomicAdd(&acc[curmb * 128 + 2 * l + 1], s1);
  }
}

// ================= LEGACY (round-2, proven) pipeline for small ws ============
#define LDK 130
__global__ __launch_bounds__(512, 2) void k_attn_v(
    const float* __restrict__ x,
    const float* __restrict__ wq, const float* __restrict__ bq,
    const float* __restrict__ wk, const float* __restrict__ bk,
    const float* __restrict__ wv, const float* __restrict__ bv,
    const float* __restrict__ wo,
    const int* __restrict__ starts, float* __restrict__ ao, int N)
{
  __shared__ unsigned short Qs[161 * LDK];
  __shared__ unsigned short Ks[160 * LDK];
  __shared__ unsigned short Vs[160 * LDK];

  const int b = blockIdx.x >> 3, h = blockIdx.x & 7;
  const int st = starts[b];
  const int n  = starts[b + 1] - st;
  const int nq = n + 1;
  const float* X = x + (size_t)st * 128;
  const int t = threadIdx.x;
  const int k = t & 127, sg = t >> 7;
  const int w = t >> 6,  l = t & 63;

  {
    const float bqv = bq[h * 128 + k], bkv = bk[h * 128 + k], bvv = bv[h * 128 + k];
    const float* wqc = wq + h * 128 + k;
    const float* wkc = wk + h * 128 + k;
    const float* wvc = wv + h * 128 + k;
    const int per = (nq + 3) >> 2;
    const int r0  = sg * per;
    for (int cch = 0; cch < 3; ++cch){
      const int rb = r0 + cch * 16;
      if (rb >= nq) break;
      const float4* xrp[16];
      #pragma unroll
      for (int i = 0; i < 16; ++i){
        int rr = rb + i; int rc = rr < n ? rr : (n - 1);
        xrp[i] = (const float4*)X + (size_t)rc * 32;
      }
      float aq[16], ak[16], av[16];
      #pragma unroll
      for (int i = 0; i < 16; ++i){ aq[i] = bqv; ak[i] = bkv; av[i] = bvv; }
      #pragma unroll 1
      for (int dq = 0; dq < 32; ++dq){
        float4 xv[16];
        #pragma unroll
        for (int i = 0; i < 16; ++i) xv[i] = xrp[i][dq];
        #pragma unroll
        for (int e = 0; e < 4; ++e){
          const int d = dq * 4 + e;
          const float wqv = wqc[d * 1024];
          const float wkv = wkc[d * 1024];
          const float wvv = wvc[d * 1024];
          #pragma unroll
          for (int i = 0; i < 16; ++i){
            const float xs = (e == 0) ? xv[i].x : (e == 1) ? xv[i].y : (e == 2) ? xv[i].z : xv[i].w;
            aq[i] = fmaf(xs, wqv, aq[i]);
            ak[i] = fmaf(xs, wkv, ak[i]);
            av[i] = fmaf(xs, wvv, av[i]);
          }
        }
      }
      #pragma unroll
      for (int i = 0; i < 16; ++i){
        const int rr = rb + i;
        if (rr < n){
          Qs[rr * LDK + k] = f2bf(aq[i]);
          Ks[rr * LDK + k] = f2bf(ak[i]);
          Vs[rr * LDK + k] = f2bf(av[i]);
        } else if (rr == n){
          Qs[rr * LDK + k] = f2bf(bqv);
        }
      }
    }
  }
  __syncthreads();

  const float SCALE = 0.0883883476483184f;
  const int itn = (nq + 7) >> 3;
  for (int it = 0; it < itn; ++it){
    const int sq = w + it * 8;
    if (sq < nq){
      const unsigned* qrow = (const unsigned*)(Qs + sq * LDK);
      const int j0 = l, j1 = l + 64, j2 = l + 128;
      const unsigned* k0r = (const unsigned*)(Ks + j0 * LDK);
      const unsigned* k1r = (const unsigned*)(Ks + j1 * LDK);
      const unsigned* k2r = (const unsigned*)(Ks + (j2 < 160 ? j2 : 159) * LDK);
      float a0 = 0.f, a1 = 0.f, a2 = 0.f;
      #pragma unroll 8
      for (int kk = 0; kk < 64; ++kk){
        const unsigned uq = qrow[kk];
        const float ql = bf_lo(uq), qh = bf_hi(uq);
        const unsigned u0 = k0r[kk], u1 = k1r[kk], u2 = k2r[kk];
        a0 += ql * bf_lo(u0) + qh * bf_hi(u0);
        a1 += ql * bf_lo(u1) + qh * bf_hi(u1);
        a2 += ql * bf_lo(u2) + qh * bf_hi(u2);
      }
      const float s0 = (j0 < n) ? a0 * SCALE : -1e30f;
      const float s1 = (j1 < n) ? a1 * SCALE : -1e30f;
      const float s2 = (j2 < n) ? a2 * SCALE : -1e30f;
      const float m  = wredmax(fmaxf(s0, fmaxf(s1, s2)));
      const float e0 = __expf(s0 - m), e1 = __expf(s1 - m), e2 = __expf(s2 - m);
      const float inv = 1.f / wredsum(e0 + e1 + e2);
      const float p0 = e0 * inv, p1 = e1 * inv, p2 = e2 * inv;
      float o0 = 0.f, o1 = 0.f;
      const unsigned short* vp = Vs + 2 * l;
      #pragma unroll 4
      for (int j = 0; j < 64; ++j){
        const float pj = __shfl(p0, j, 64);
        const unsigned uv = *(const unsigned*)(vp + j * LDK);
        o0 = fmaf(pj, bf_lo(uv), o0);
        o1 = fmaf(pj, bf_hi(uv), o1);
      }
      const int n1 = n < 128 ? n : 128;
      #pragma unroll 4
      for (int j = 64; j < n1; ++j){
        const float pj = __shfl(p1, j - 64, 64);
        const unsigned uv = *(const unsigned*)(vp + j * LDK);
        o0 = fmaf(pj, bf_lo(uv), o0);
        o1 = fmaf(pj, bf_hi(uv), o1);
      }
      #pragma unroll 4
      for (int j = 128; j < n; ++j){
        const float pj = __shfl(p2, j - 128, 64);
        const unsigned uv = *(const unsigned*)(vp + j * LDK);
        o0 = fmaf(pj, bf_lo(uv), o0);
        o1 = fmaf(pj, bf_hi(uv), o1);
      }
      ((unsigned*)(Qs + sq * LDK))[l] = pk2(o0, o1);
    }
  }
  __syncthreads();

  {
    const int d = k;
    const int per = (nq + 3) >> 2;
    const int r0  = sg * per;
    const int rend = min(r0 + per, nq);
    const float* wop = wo + (size_t)(h * 128) * 128 + d;
    for (int cch = 0; cch < 3; ++cch){
      const int rb = r0 + cch * 16;
      if (rb >= rend) break;
      int roff[16];
      #pragma unroll
      for (int i = 0; i < 16; ++i){
        int rr = rb + i;
        roff[i] = (rr < nq ? rr : (nq - 1)) * LDK;
      }
      float acc[16];
      #pragma unroll
      for (int i = 0; i < 16; ++i) acc[i] = 0.f;
      #pragma unroll 1
      for (int kk = 0; kk < 128; ++kk){
        const float wv2 = wop[(size_t)kk * 128];
        #pragma unroll
        for (int i = 0; i < 16; ++i)
          acc[i] = fmaf(bf2f(Qs[roff[i] + kk]), wv2, acc[i]);
      }
      #pragma unroll
      for (int i = 0; i < 16; ++i){
        const int rr = rb + i;
        if (rr < rend){
          const int grow = (rr < n) ? (st + rr) : (N + b);
          atomicAdd(&ao[(size_t)grow * 128 + d], acc[i]);
        }
      }
    }
  }
}

__global__ __launch_bounds__(512, 2) void k_ffn_v(
    const float* __restrict__ x, const int* __restrict__ mol,
    const float* __restrict__ ao, const float* __restrict__ bo,
    const float* __restrict__ w1, const float* __restrict__ b1,
    const float* __restrict__ w2, const float* __restrict__ b2,
    const float* __restrict__ g1, const float* __restrict__ be1,
    const float* __restrict__ g2, const float* __restrict__ be2,
    const int* __restrict__ starts, float* __restrict__ acc,
    int N, int NR)
{
  __shared__ unsigned short Ws[32768];
  __shared__ float h1s[32][128];
  __shared__ unsigned short ts[32][256];
  const int t = threadIdx.x, w = t >> 6, l = t & 63;
  const int rbase = blockIdx.x * 32;

  for (int i = t; i < 32768; i += 512) Ws[i] = f2bf(w1[i]);
  __syncthreads();

  for (int it = 0; it < 4; ++it){
    const int r = w + it * 8;
    const int row = rbase + r;
    if (row < NR){
      float x0 = 0.f, x1 = 0.f;
      if (row < N){
        x0 = x[(size_t)row * 128 + l];
        x1 = x[(size_t)row * 128 + l + 64];
      }
      const float a0 = x0 + ao[(size_t)row * 128 + l]      + bo[l];
      const float a1 = x1 + ao[(size_t)row * 128 + l + 64] + bo[l + 64];
      const float mean = wredsum(a0 + a1) * (1.f / 128.f);
      const float d0 = a0 - mean, d1 = a1 - mean;
      const float var = wredsum(d0 * d0 + d1 * d1) * (1.f / 128.f);
      const float inv = rsqrtf(var + 1e-3f);
      h1s[r][l]      = d0 * inv * g1[l]      + be1[l];
      h1s[r][l + 64] = d1 * inv * g1[l + 64] + be1[l + 64];
    }
    __syncthreads();
    if (row < NR){
      float tj0 = b1[l], tj1 = b1[l + 64], tj2 = b1[l + 128], tj3 = b1[l + 192];
      #pragma unroll 4
      for (int d = 0; d < 128; ++d){
        const float hv = h1s[r][d];
        tj0 = fmaf(hv, bf2f(Ws[d * 256 + l]),       tj0);
        tj1 = fmaf(hv, bf2f(Ws[d * 256 + l + 64]),  tj1);
        tj2 = fmaf(hv, bf2f(Ws[d * 256 + l + 128]), tj2);
        tj3 = fmaf(hv, bf2f(Ws[d * 256 + l + 192]), tj3);
      }
      ts[r][l]       = f2bf(fmaxf(tj0, 0.f));
      ts[r][l + 64]  = f2bf(fmaxf(tj1, 0.f));
      ts[r][l + 128] = f2bf(fmaxf(tj2, 0.f));
      ts[r][l + 192] = f2bf(fmaxf(tj3, 0.f));
    }
  }
  __syncthreads();
  for (int i = t; i < 32768; i += 512) Ws[i] = f2bf(w2[i]);
  __syncthreads();

  for (int it = 0; it < 4; ++it){
    const int r = w + it * 8;
    const int row = rbase + r;
    if (row >= NR) continue;
    float f0 = b2[l], f1 = b2[l + 64];
    #pragma unroll 4
    for (int j = 0; j < 256; ++j){
      const float tv = bf2f(ts[r][j]);
      f0 = fmaf(tv, bf2f(Ws[j * 128 + l]),      f0);
      f1 = fmaf(tv, bf2f(Ws[j * 128 + l + 64]), f1);
    }
    const float r0 = h1s[r][l] + f0, r1 = h1s[r][l + 64] + f1;
    const float mean = wredsum(r0 + r1) * (1.f / 128.f);
    const float d0 = r0 - mean, d1 = r1 - mean;
    const float var = wredsum(d0 * d0 + d1 * d1) * (1.f / 128.f);
    const float inv = rsqrtf(var + 1e-3f);
    const float o0 = d0 * inv * g2[l]      + be2[l];
    const float o1 = d1 * inv * g2[l + 64] + be2[l + 64];
    int mb; float wgt;
    if (row < N){ mb = mol[row]; wgt = 1.f; }
    else { mb = row - N; wgt = (float)(160 - (starts[mb + 1] - starts[mb])); }
    atomicAdd(&acc[mb * 128 + l],      o0 * wgt);
    atomicAdd(&acc[mb * 128 + l + 64], o1 * wgt);
  }
}

// ---------------- kernel D: divide by true atom count ------------------------
__global__ void k_out(const float* __restrict__ acc, const int* __restrict__ starts,
                      float* __restrict__ out){
  const int i = blockIdx.x * blockDim.x + threadIdx.x;
  if (i < 256 * 128){
    const int b = i >> 7;
    out[i] = acc[i] / (float)(starts[b + 1] - starts[b]);
  }
}

extern "C" void kernel_launch(void* const* d_in, const int* in_sizes, int n_in,
                              void* d_out, int out_size, void* d_ws, size_t ws_size,
                              hipStream_t stream)
{
  const float* x   = (const float*)d_in[0];
  const int*   mol = (const int*)d_in[1];
  const float* wq  = (const float*)d_in[2];
  const float* bq  = (const float*)d_in[3];
  const float* wk  = (const float*)d_in[4];
  const float* bk  = (const float*)d_in[5];
  const float* wv  = (const float*)d_in[6];
  const float* bv  = (const float*)d_in[7];
  const float* wo  = (const float*)d_in[8];
  const float* bo  = (const float*)d_in[9];
  const float* w1  = (const float*)d_in[10];
  const float* b1  = (const float*)d_in[11];
  const float* w2  = (const float*)d_in[12];
  const float* b2  = (const float*)d_in[13];
  const float* g1  = (const float*)d_in[14];
  const float* be1 = (const float*)d_in[15];
  const float* g2  = (const float*)d_in[16];
  const float* be2 = (const float*)d_in[17];

  const int N  = in_sizes[1];        // 32706
  const int NR = N + 256;            // + one phantom row per molecule

  const size_t off_wt  = 2048;
  const size_t off_w1t = off_wt  + 1048576;
  const size_t off_w2t = off_w1t + 65536;
  const size_t off_acc = off_w2t + 65536;
  const size_t off_ao  = off_acc + 131072;
  const size_t off_q   = off_ao + (size_t)8 * NR * 128 * 2;
  const size_t need3 = off_q + (size_t)2048 * 45056;        // ~161 MB
  const size_t need2 = off_q;                               // ~68.8 MB
  const size_t need1 = off_ao + (size_t)NR * 128 * 4;       // ~18.2 MB
  const int mode = (ws_size >= need3) ? 3 : (ws_size >= need2) ? 2
                 : (ws_size >= need1) ? 1 : 0;

  char* wsp = (char*)d_ws;
  int* starts = (int*)wsp;

  if (mode >= 1){
    unsigned short* wt  = (unsigned short*)(wsp + off_wt);
    unsigned short* w1t = (unsigned short*)(wsp + off_w1t);
    unsigned short* w2t = (unsigned short*)(wsp + off_w2t);
    float*          acc = (float*)(wsp + off_acc);
    unsigned short* aoh = (unsigned short*)(wsp + off_ao);
    float*          aof = (float*)(wsp + off_ao);
    unsigned short* qg  = (unsigned short*)(wsp + off_q);
    const int useslab = (mode >= 2) ? 1 : 0;

    hipMemsetAsync(acc, 0, 131072, stream);
    if (!useslab) hipMemsetAsync(aof, 0, (size_t)NR * 128 * 4, stream);
    k_prep_all<<<577, 256, 0, stream>>>(wq, wk, wv, wo, w1, w2, mol, N,
                                        wt, w1t, w2t, starts);
    if (mode == 3)
      k_attn3<<<2048, 512, 0, stream>>>(x, wt, bq, bk, bv, starts, aoh, qg, N, NR);
    else
      k_attn<<<2048, 512, 0, stream>>>(x, wt, bq, bk, bv, starts, aoh, aof, useslab, N, NR);
    k_ffn<<<(NR + 63) / 64, 512, 0, stream>>>(x, mol, aoh, aof, useslab, bo, w1t, w2t,
                                              b1, b2, g1, be1, g2, be2, starts, acc, N, NR);
    k_out<<<(256 * 128 + 255) / 256, 256, 0, stream>>>(acc, starts, (float*)d_out);
  } else {
    float* ao  = (float*)(wsp + 2048);
    float* acc = (float*)(wsp + 2048 + (size_t)NR * 128 * 4);
    hipMemsetAsync(ao, 0, (size_t)(NR + 256) * 128 * 4, stream);
    k_starts<<<1, 512, 0, stream>>>(mol, N, starts);
    k_attn_v<<<256 * 8, 512, 0, stream>>>(x, wq, bq, wk, bk, wv, bv, wo, starts, ao, N);
    k_ffn_v<<<(NR + 31) / 32, 512, 0, stream>>>(x, mol, ao, bo, w1, b1, w2, b2,
                                                g1, be1, g2, be2, starts, acc, N, NR);
    k_out<<<(256 * 128 + 255) / 256, 256, 0, stream>>>(acc, starts, (float*)d_out);
  }
}